// Round 1
// baseline (172.419 us; speedup 1.0000x reference)
//
#include <hip/hip_runtime.h>
#include <math.h>

#define NNODES 4096
#define CC     128
#define KCL    32
#define MM     128
#define EE     65536
#define HH     8
#define DD     64
#define INNERD 512

// ---------------- adjacency bitmask ----------------
__global__ __launch_bounds__(256) void build_adj_kernel(const int* __restrict__ ei,
                                                        unsigned* __restrict__ adjw) {
  int e = blockIdx.x * 256 + threadIdx.x;
  if (e >= EE) return;
  int s = ei[e], d = ei[EE + e];
  int cs = s >> 7, cd = d >> 7;
  if (cs == cd) {
    int flat = cs * (MM * MM) + (s & 127) * MM + (d & 127);
    atomicOr(adjw + (flat >> 5), 1u << (flat & 31));
  }
}

// ---------------- e0/e1 + rotary tables ----------------
// e01[0..511] = adj_emb[0] @ We + be ; e01[512..1023] = adj_emb[1] @ We + be
// cosT/sinT layout [p][i] : p in [0,32), i in [0,128)
__global__ __launch_bounds__(256) void prep_kernel(const float* __restrict__ adj_emb,
                                                   const float* __restrict__ We,
                                                   const float* __restrict__ be,
                                                   float* __restrict__ e01,
                                                   float* __restrict__ cosT,
                                                   float* __restrict__ sinT) {
  int g = blockIdx.x * 256 + threadIdx.x;
  if (g < 1024) {
    int which = g >> 9, col = g & 511;
    float a = 0.f;
    for (int c = 0; c < CC; ++c) a += adj_emb[which * CC + c] * We[(size_t)c * INNERD + col];
    e01[g] = a + be[col];
  } else {
    int idx = g - 1024;
    if (idx < 4096) {
      int p = idx >> 7, i = idx & 127;
      float inv = exp2f(-(float)p * (13.287712379549449f / 32.0f)); // 10000^(-p/32)
      float ang = (float)i * inv;
      cosT[idx] = cosf(ang);
      sinT[idx] = sinf(ang);
    }
  }
}

// ---------------- LayerNorm (wave per row) ----------------
__global__ __launch_bounds__(256) void ln_kernel(const float* __restrict__ in,
                                                 const int* __restrict__ cl,
                                                 const float* __restrict__ gg,
                                                 const float* __restrict__ bb,
                                                 float* __restrict__ y) {
  int row = blockIdx.x * 4 + (threadIdx.x >> 6);
  int lane = threadIdx.x & 63;
  int src = cl ? cl[row] : row;
  const float* p = in + (size_t)src * CC;
  float2 v = *(const float2*)(p + lane * 2);
  float s = v.x + v.y, q = v.x * v.x + v.y * v.y;
#pragma unroll
  for (int o = 32; o; o >>= 1) { s += __shfl_xor(s, o); q += __shfl_xor(q, o); }
  float mu = s * (1.0f / CC);
  float var = q * (1.0f / CC) - mu * mu;
  float rs = rsqrtf(var + 1e-5f);
  float2 g2 = *(const float2*)(gg + lane * 2);
  float2 b2 = *(const float2*)(bb + lane * 2);
  float2 o2;
  o2.x = (v.x - mu) * rs * g2.x + b2.x;
  o2.y = (v.y - mu) * rs * g2.y + b2.y;
  *(float2*)(y + (size_t)row * CC + lane * 2) = o2;
}

// ---------------- fp32 GEMM: C = A[M,K]@B[K,N] + bias, optional exact GELU --------
template <int ACT>
__global__ __launch_bounds__(256) void gemm_bias_kernel(const float* __restrict__ A,
                                                        const float* __restrict__ B,
                                                        const float* __restrict__ bias,
                                                        float* __restrict__ Cout,
                                                        int Kdim, int Ncols) {
  __shared__ float As[16][68];
  __shared__ float Bs[16][68];
  int t = threadIdx.x;
  int n0 = blockIdx.x * 64;
  int m0 = blockIdx.y * 64;
  int ty = t >> 4, tx = t & 15;
  float acc[4][4] = {};
  for (int k0 = 0; k0 < Kdim; k0 += 16) {
#pragma unroll
    for (int e = 0; e < 4; ++e) {
      int f = e * 256 + t;
      int m = f >> 4, kk = f & 15;
      As[kk][m] = A[(size_t)(m0 + m) * Kdim + k0 + kk];
    }
#pragma unroll
    for (int e = 0; e < 4; ++e) {
      int f = e * 256 + t;
      int kk = f >> 6, n = f & 63;
      Bs[kk][n] = B[(size_t)(k0 + kk) * Ncols + n0 + n];
    }
    __syncthreads();
#pragma unroll
    for (int kk = 0; kk < 16; ++kk) {
      float4 a4 = *(const float4*)&As[kk][ty * 4];
      float4 b4 = *(const float4*)&Bs[kk][tx * 4];
      float av[4] = {a4.x, a4.y, a4.z, a4.w};
      float bv[4] = {b4.x, b4.y, b4.z, b4.w};
#pragma unroll
      for (int r = 0; r < 4; ++r)
#pragma unroll
        for (int c = 0; c < 4; ++c) acc[r][c] += av[r] * bv[c];
    }
    __syncthreads();
  }
#pragma unroll
  for (int r = 0; r < 4; ++r) {
    float4 o;
    float* op = (float*)&o;
#pragma unroll
    for (int c = 0; c < 4; ++c) {
      float v = acc[r][c] + bias[n0 + tx * 4 + c];
      if (ACT == 1) v = 0.5f * v * (1.0f + erff(v * 0.70710678118654752f));
      op[c] = v;
    }
    *(float4*)&Cout[(size_t)(m0 + ty * 4 + r) * Ncols + n0 + tx * 4] = o;
  }
}

// ---------------- fused attention per (cluster, head) ----------------
__global__ __launch_bounds__(256) void attn_kernel(const float* __restrict__ Pq,
                                                   const float* __restrict__ Pkv,
                                                   const unsigned* __restrict__ adjw,
                                                   const float* __restrict__ e01,
                                                   const float* __restrict__ cosT,
                                                   const float* __restrict__ sinT,
                                                   float* __restrict__ AO) {
  __shared__ float qT[64][133];   // transposed [d][i]
  __shared__ float kT[64][133];
  __shared__ float simL[128][129];
  __shared__ unsigned adjL[512];
  __shared__ float qe0L[128], qe1L[128], sL[128];
  __shared__ float e0s[64], e1s[64];

  int t = threadIdx.x;
  int kc = blockIdx.x >> 3, h = blockIdx.x & 7;

  const float* qbase = Pq + (size_t)kc * 128 * INNERD + h * DD;
  const float* kbase = Pkv + (size_t)kc * 128 * (2 * INNERD) + h * DD;
  const float* vbase = kbase + INNERD;

  // load q,k transposed
  for (int f = t; f < 2048; f += 256) {
    int i = f >> 4, qd = (f & 15) * 4;
    float4 qv = *(const float4*)(qbase + (size_t)i * INNERD + qd);
    qT[qd + 0][i] = qv.x; qT[qd + 1][i] = qv.y; qT[qd + 2][i] = qv.z; qT[qd + 3][i] = qv.w;
    float4 kv = *(const float4*)(kbase + (size_t)i * (2 * INNERD) + qd);
    kT[qd + 0][i] = kv.x; kT[qd + 1][i] = kv.y; kT[qd + 2][i] = kv.z; kT[qd + 3][i] = kv.w;
  }
  for (int f = t; f < 512; f += 256) adjL[f] = adjw[kc * 512 + f];
  if (t < 64) { e0s[t] = e01[h * DD + t]; e1s[t] = e01[512 + h * DD + t]; }
  __syncthreads();

  // rotary in LDS (q and k); idx = p*128 + i
  for (int idx = t; idx < 4096; idx += 256) {
    int p = idx >> 7, i = idx & 127;
    float cv = cosT[idx], sv = sinT[idx];
    float qa = qT[2 * p][i], qb = qT[2 * p + 1][i];
    qT[2 * p][i]     = qa * cv - qb * sv;
    qT[2 * p + 1][i] = qb * cv + qa * sv;
    float ka = kT[2 * p][i], kb = kT[2 * p + 1][i];
    kT[2 * p][i]     = ka * cv - kb * sv;
    kT[2 * p + 1][i] = kb * cv + ka * sv;
  }
  __syncthreads();

  // per-row q·e0, q·e1
  if (t < 128) {
    float a0 = 0.f, a1 = 0.f;
    for (int d = 0; d < 64; ++d) {
      float qv = qT[d][t];
      a0 += qv * e0s[d];
      a1 += qv * e1s[d];
    }
    qe0L[t] = a0; qe1L[t] = a1;
  }
  __syncthreads();

  // QK^T : 16x16 threads, 8x8 strided micro-tile
  int ti = t >> 4, tj = t & 15;
  {
    float acc[8][8] = {};
    for (int d = 0; d < 64; ++d) {
      float aR[8], bR[8];
#pragma unroll
      for (int r = 0; r < 8; ++r) aR[r] = qT[d][ti + 16 * r];
#pragma unroll
      for (int c = 0; c < 8; ++c) bR[c] = kT[d][tj + 16 * c];
#pragma unroll
      for (int r = 0; r < 8; ++r)
#pragma unroll
        for (int c = 0; c < 8; ++c) acc[r][c] += aR[r] * bR[c];
    }
#pragma unroll
    for (int r = 0; r < 8; ++r) {
      int i = ti + 16 * r;
      float q0 = qe0L[i], q1 = qe1L[i];
#pragma unroll
      for (int c = 0; c < 8; ++c) {
        int j = tj + 16 * c;
        unsigned bit = (adjL[i * 4 + (j >> 5)] >> (j & 31)) & 1u;
        simL[i][j] = (acc[r][c] + (bit ? q1 : q0)) * 0.125f;
      }
    }
  }
  __syncthreads();

  // load V into the qT/kT LDS space (no simL dependency), then softmax
  float* vL = &qT[0][0];  // 128*68 floats fits in qT+kT (2*64*133)
  for (int f = t; f < 2048; f += 256) {
    int j = f >> 4, qd = (f & 15) * 4;
    float4 vv = *(const float4*)(vbase + (size_t)j * (2 * INNERD) + qd);
    *(float4*)&vL[j * 68 + qd] = vv;
  }
  {
    int i = t >> 1, half = t & 1, j0 = half * 64;
    float m = -1e30f;
    for (int j = 0; j < 64; ++j) m = fmaxf(m, simL[i][j0 + j]);
    m = fmaxf(m, __shfl_xor(m, 1));
    float sum = 0.f;
    for (int j = 0; j < 64; ++j) {
      float p = __expf(simL[i][j0 + j] - m);
      simL[i][j0 + j] = p;
      sum += p;
    }
    sum += __shfl_xor(sum, 1);
    float inv = 1.0f / sum;
    float sadj = 0.f;
    for (int j = 0; j < 64; ++j) {
      int jj = j0 + j;
      float p = simL[i][jj] * inv;
      simL[i][jj] = p;
      unsigned bit = (adjL[i * 4 + (jj >> 5)] >> (jj & 31)) & 1u;
      sadj += bit ? p : 0.f;
    }
    sadj += __shfl_xor(sadj, 1);
    if (half == 0) sL[i] = sadj;
  }
  __syncthreads();

  // PV: thread -> 8 rows (strided) x 4 cols
  {
    float acc[8][4] = {};
    int dbase = tj * 4;
    for (int j = 0; j < 128; ++j) {
      float4 vv = *(const float4*)&vL[j * 68 + dbase];
#pragma unroll
      for (int r = 0; r < 8; ++r) {
        float p = simL[ti + 16 * r][j];
        acc[r][0] += p * vv.x;
        acc[r][1] += p * vv.y;
        acc[r][2] += p * vv.z;
        acc[r][3] += p * vv.w;
      }
    }
#pragma unroll
    for (int r = 0; r < 8; ++r) {
      int i = ti + 16 * r;
      float s = sL[i];
      float4 o;
      o.x = acc[r][0] + e0s[dbase + 0] * (1.0f - s) + e1s[dbase + 0] * s;
      o.y = acc[r][1] + e0s[dbase + 1] * (1.0f - s) + e1s[dbase + 1] * s;
      o.z = acc[r][2] + e0s[dbase + 2] * (1.0f - s) + e1s[dbase + 2] * s;
      o.w = acc[r][3] + e0s[dbase + 3] * (1.0f - s) + e1s[dbase + 3] * s;
      *(float4*)(AO + (size_t)(kc * 128 + i) * INNERD + h * DD + dbase) = o;
    }
  }
}

// ---------------- gated residual (wave per row) ----------------
__global__ __launch_bounds__(256) void gated_res_kernel(const float* __restrict__ xn,
                                                        const float* __restrict__ resbuf,
                                                        const int* __restrict__ cl,
                                                        const float* __restrict__ Wg,
                                                        float* __restrict__ out) {
  int row = blockIdx.x * 4 + (threadIdx.x >> 6);
  int lane = threadIdx.x & 63;
  int src = cl ? cl[row] : row;
  float2 a = *(const float2*)(xn + (size_t)row * CC + lane * 2);
  float2 r = *(const float2*)(resbuf + (size_t)src * CC + lane * 2);
  int c = lane * 2;
  float w0a = Wg[c] + Wg[256 + c], w0b = Wg[c + 1] + Wg[256 + c + 1];
  float w1a = Wg[128 + c] - Wg[256 + c], w1b = Wg[128 + c + 1] - Wg[256 + c + 1];
  float dot = a.x * w0a + a.y * w0b + r.x * w1a + r.y * w1b;
#pragma unroll
  for (int o = 32; o; o >>= 1) dot += __shfl_xor(dot, o);
  float g = 1.0f / (1.0f + __expf(-dot));
  float2 o2;
  o2.x = a.x * g + r.x * (1.0f - g);
  o2.y = a.y * g + r.y * (1.0f - g);
  *(float2*)(out + (size_t)row * CC + lane * 2) = o2;
}

// ---------------- final: gated residual 2 + scatter-add into x ----------------
__global__ __launch_bounds__(256) void final_kernel(const float* __restrict__ ff,
                                                    const float* __restrict__ n1,
                                                    const float* __restrict__ x,
                                                    const int* __restrict__ cl,
                                                    const float* __restrict__ Wg,
                                                    float* __restrict__ out) {
  int row = blockIdx.x * 4 + (threadIdx.x >> 6);
  int lane = threadIdx.x & 63;
  int src = cl[row];
  float2 a = *(const float2*)(ff + (size_t)row * CC + lane * 2);
  float2 r = *(const float2*)(n1 + (size_t)row * CC + lane * 2);
  int c = lane * 2;
  float w0a = Wg[c] + Wg[256 + c], w0b = Wg[c + 1] + Wg[256 + c + 1];
  float w1a = Wg[128 + c] - Wg[256 + c], w1b = Wg[128 + c + 1] - Wg[256 + c + 1];
  float dot = a.x * w0a + a.y * w0b + r.x * w1a + r.y * w1b;
#pragma unroll
  for (int o = 32; o; o >>= 1) dot += __shfl_xor(dot, o);
  float g = 1.0f / (1.0f + __expf(-dot));
  float2 xv = *(const float2*)(x + (size_t)src * CC + lane * 2);
  float2 o2;
  o2.x = xv.x + a.x * g + r.x * (1.0f - g);
  o2.y = xv.y + a.y * g + r.y * (1.0f - g);
  *(float2*)(out + (size_t)src * CC + lane * 2) = o2;
}

extern "C" void kernel_launch(void* const* d_in, const int* in_sizes, int n_in,
                              void* d_out, int out_size, void* d_ws, size_t ws_size,
                              hipStream_t stream) {
  const float* x       = (const float*)d_in[0];
  const int*   edge    = (const int*)d_in[1];
  const int*   clusters= (const int*)d_in[2];
  const float* adj_emb = (const float*)d_in[3];
  const float* ln1_g   = (const float*)d_in[4];
  const float* ln1_b   = (const float*)d_in[5];
  const float* Wq      = (const float*)d_in[6];
  const float* bq      = (const float*)d_in[7];
  const float* Wkv     = (const float*)d_in[8];
  const float* bkv     = (const float*)d_in[9];
  const float* We      = (const float*)d_in[10];
  const float* be      = (const float*)d_in[11];
  const float* Wo      = (const float*)d_in[12];
  const float* bo      = (const float*)d_in[13];
  const float* gate1   = (const float*)d_in[14];
  const float* ln2_g   = (const float*)d_in[15];
  const float* ln2_b   = (const float*)d_in[16];
  const float* W1      = (const float*)d_in[17];
  const float* b1      = (const float*)d_in[18];
  const float* W2      = (const float*)d_in[19];
  const float* b2      = (const float*)d_in[20];
  const float* gate2   = (const float*)d_in[21];

  char* wsb = (char*)d_ws;
  unsigned* adjw = (unsigned*)wsb;                       // 65536 B
  float* e01  = (float*)(wsb + 65536);                   // 4096 B
  float* cosT = (float*)(wsb + 65536 + 4096);            // 16384 B
  float* sinT = cosT + 4096;                             // 16384 B
  float* yb   = sinT + 4096;                             // 2 MB
  float* Pq   = yb + (size_t)NNODES * CC;                // 8 MB
  float* Pkv  = Pq + (size_t)NNODES * INNERD;            // 16 MB
  float* AO   = Pkv + (size_t)NNODES * 2 * INNERD;       // 8 MB
  float* t1   = AO + (size_t)NNODES * INNERD;            // 2 MB
  float* n1   = t1 + (size_t)NNODES * CC;                // 2 MB
  float* ffh  = Pq;   // reuse (Pq dead after attention)
  float* ffo  = t1;   // reuse (t1 dead after gated1)
  float* y2   = yb;   // reuse

  hipMemsetAsync(adjw, 0, 65536, stream);
  build_adj_kernel<<<EE / 256, 256, 0, stream>>>(edge, adjw);
  prep_kernel<<<20, 256, 0, stream>>>(adj_emb, We, be, e01, cosT, sinT);
  ln_kernel<<<NNODES / 4, 256, 0, stream>>>(x, clusters, ln1_g, ln1_b, yb);
  gemm_bias_kernel<0><<<dim3(INNERD / 64, NNODES / 64), 256, 0, stream>>>(yb, Wq, bq, Pq, CC, INNERD);
  gemm_bias_kernel<0><<<dim3(2 * INNERD / 64, NNODES / 64), 256, 0, stream>>>(yb, Wkv, bkv, Pkv, CC, 2 * INNERD);
  attn_kernel<<<KCL * HH, 256, 0, stream>>>(Pq, Pkv, adjw, e01, cosT, sinT, AO);
  gemm_bias_kernel<0><<<dim3(CC / 64, NNODES / 64), 256, 0, stream>>>(AO, Wo, bo, t1, INNERD, CC);
  gated_res_kernel<<<NNODES / 4, 256, 0, stream>>>(t1, x, clusters, gate1, n1);
  ln_kernel<<<NNODES / 4, 256, 0, stream>>>(n1, nullptr, ln2_g, ln2_b, y2);
  gemm_bias_kernel<1><<<dim3(INNERD / 64, NNODES / 64), 256, 0, stream>>>(y2, W1, b1, ffh, CC, INNERD);
  gemm_bias_kernel<0><<<dim3(CC / 64, NNODES / 64), 256, 0, stream>>>(ffh, W2, b2, ffo, INNERD, CC);
  final_kernel<<<NNODES / 4, 256, 0, stream>>>(ffo, n1, x, clusters, gate2, (float*)d_out);
}

// Round 2
// 108.617 us; speedup vs baseline: 1.5874x; 1.5874x over previous
//
#include <hip/hip_runtime.h>
#include <math.h>

#define NNODES 4096
#define CC     128
#define KCL    32
#define MM     128
#define EE     65536
#define HH     8
#define DD     64
#define INNERD 512

typedef __attribute__((ext_vector_type(8))) short short8;
typedef __attribute__((ext_vector_type(4))) float f32x4;

__device__ __forceinline__ float bf2f(ushort u) { return __uint_as_float(((unsigned)u) << 16); }
__device__ __forceinline__ ushort f2bf(float f) {
  unsigned b = __float_as_uint(f);
  return (ushort)((b + 0x7FFFu + ((b >> 16) & 1u)) >> 16);
}

// ---------------- adjacency bitmask ----------------
__global__ __launch_bounds__(256) void build_adj_kernel(const int* __restrict__ ei,
                                                        unsigned* __restrict__ adjw) {
  int e = blockIdx.x * 256 + threadIdx.x;
  if (e >= EE) return;
  int s = ei[e], d = ei[EE + e];
  int cs = s >> 7, cd = d >> 7;
  if (cs == cd) {
    int flat = cs * (MM * MM) + (s & 127) * MM + (d & 127);
    atomicOr(adjw + (flat >> 5), 1u << (flat & 31));
  }
}

// ---------------- e0/e1 + rotary tables ----------------
__global__ __launch_bounds__(256) void prep_kernel(const float* __restrict__ adj_emb,
                                                   const float* __restrict__ We,
                                                   const float* __restrict__ be,
                                                   float* __restrict__ e01,
                                                   float* __restrict__ cosT,
                                                   float* __restrict__ sinT) {
  int g = blockIdx.x * 256 + threadIdx.x;
  if (g < 1024) {
    int which = g >> 9, col = g & 511;
    float a = 0.f;
    for (int c = 0; c < CC; ++c) a += adj_emb[which * CC + c] * We[(size_t)c * INNERD + col];
    e01[g] = a + be[col];
  } else {
    int idx = g - 1024;
    if (idx < 4096) {
      int p = idx >> 7, i = idx & 127;
      float inv = exp2f(-(float)p * (13.287712379549449f / 32.0f)); // 10000^(-p/32)
      float ang = (float)i * inv;
      cosT[idx] = cosf(ang);
      sinT[idx] = sinf(ang);
    }
  }
}

// ---------------- weight convert+transpose to bf16 [N][K] ----------------
__global__ __launch_bounds__(256) void wconv_kernel(const float* __restrict__ Wq,
                                                    const float* __restrict__ Wkv,
                                                    const float* __restrict__ Wo,
                                                    const float* __restrict__ W1,
                                                    const float* __restrict__ W2,
                                                    ushort* __restrict__ WqT,
                                                    ushort* __restrict__ WkvT,
                                                    ushort* __restrict__ WoT,
                                                    ushort* __restrict__ W1T,
                                                    ushort* __restrict__ W2T) {
  int g = blockIdx.x * 256 + threadIdx.x;  // 393216 total
  const float* src; ushort* dst; int idx, sh, N;
  if (g < 65536)       { src = Wq;  dst = WqT;  idx = g;          sh = 7; N = 512; }
  else if (g < 196608) { src = Wkv; dst = WkvT; idx = g - 65536;  sh = 7; N = 1024; }
  else if (g < 262144) { src = Wo;  dst = WoT;  idx = g - 196608; sh = 9; N = 128; }
  else if (g < 327680) { src = W1;  dst = W1T;  idx = g - 262144; sh = 7; N = 512; }
  else                 { src = W2;  dst = W2T;  idx = g - 327680; sh = 9; N = 128; }
  int K = 1 << sh;
  int n = idx >> sh, k = idx & (K - 1);
  dst[idx] = f2bf(src[(size_t)k * N + n]);
}

// ---------------- LayerNorm (wave per row) -> bf16 ----------------
__global__ __launch_bounds__(256) void ln_kernel(const float* __restrict__ in,
                                                 const int* __restrict__ cl,
                                                 const float* __restrict__ gg,
                                                 const float* __restrict__ bb,
                                                 ushort* __restrict__ y) {
  int row = blockIdx.x * 4 + (threadIdx.x >> 6);
  int lane = threadIdx.x & 63;
  int src = cl ? cl[row] : row;
  const float* p = in + (size_t)src * CC;
  float2 v = *(const float2*)(p + lane * 2);
  float s = v.x + v.y, q = v.x * v.x + v.y * v.y;
#pragma unroll
  for (int o = 32; o; o >>= 1) { s += __shfl_xor(s, o); q += __shfl_xor(q, o); }
  float mu = s * (1.0f / CC);
  float var = q * (1.0f / CC) - mu * mu;
  float rs = rsqrtf(var + 1e-5f);
  float2 g2 = *(const float2*)(gg + lane * 2);
  float2 b2 = *(const float2*)(bb + lane * 2);
  float ox = (v.x - mu) * rs * g2.x + b2.x;
  float oy = (v.y - mu) * rs * g2.y + b2.y;
  *(unsigned*)&y[(size_t)row * CC + lane * 2] = (unsigned)f2bf(ox) | ((unsigned)f2bf(oy) << 16);
}

// ---------------- bf16 MFMA GEMM: C = A[M,K] @ BT[N,K]^T + bias ----------------
// 128x128 tile, 4 waves (2x2), BK=32, 16x16x32 MFMA. A,BT bf16 k-contiguous.
template <int ACT, int OUTBF>
__global__ __launch_bounds__(256) void gemm_bf16_kernel(const ushort* __restrict__ A,
                                                        const ushort* __restrict__ BT,
                                                        const float* __restrict__ bias,
                                                        void* __restrict__ Cout,
                                                        int Kd, int Nd) {
  __shared__ ushort Ab[128 * 32];
  __shared__ ushort Bb[128 * 32];
  int t = threadIdx.x;
  int w = t >> 6, l = t & 63;
  int n0 = blockIdx.x * 128, m0 = blockIdx.y * 128;
  int wr = (w >> 1) * 64, wc = (w & 1) * 64;
  f32x4 acc[4][4];
#pragma unroll
  for (int mi = 0; mi < 4; ++mi)
#pragma unroll
    for (int nj = 0; nj < 4; ++nj) acc[mi][nj] = (f32x4){0.f, 0.f, 0.f, 0.f};

  for (int k0 = 0; k0 < Kd; k0 += 32) {
#pragma unroll
    for (int i = 0; i < 2; ++i) {
      int c = t + i * 256;           // 512 chunks of 8 bf16
      int r = c >> 2, kc = c & 3;
      *(uint4*)&Ab[r * 32 + kc * 8] = *(const uint4*)&A[(size_t)(m0 + r) * Kd + k0 + kc * 8];
      *(uint4*)&Bb[r * 32 + kc * 8] = *(const uint4*)&BT[(size_t)(n0 + r) * Kd + k0 + kc * 8];
    }
    __syncthreads();
    short8 aF[4], bF[4];
#pragma unroll
    for (int mi = 0; mi < 4; ++mi) aF[mi] = *(const short8*)&Ab[(wr + mi * 16 + (l & 15)) * 32 + (l >> 4) * 8];
#pragma unroll
    for (int nj = 0; nj < 4; ++nj) bF[nj] = *(const short8*)&Bb[(wc + nj * 16 + (l & 15)) * 32 + (l >> 4) * 8];
#pragma unroll
    for (int mi = 0; mi < 4; ++mi)
#pragma unroll
      for (int nj = 0; nj < 4; ++nj)
        acc[mi][nj] = __builtin_amdgcn_mfma_f32_16x16x32_bf16(aF[mi], bF[nj], acc[mi][nj], 0, 0, 0);
    __syncthreads();
  }
#pragma unroll
  for (int mi = 0; mi < 4; ++mi)
#pragma unroll
    for (int nj = 0; nj < 4; ++nj)
#pragma unroll
      for (int r = 0; r < 4; ++r) {
        int m = m0 + wr + mi * 16 + ((l >> 4) << 2) + r;
        int n = n0 + wc + nj * 16 + (l & 15);
        float v = acc[mi][nj][r] + bias[n];
        if (ACT) v = 0.5f * v * (1.0f + erff(v * 0.70710678118654752f));
        if (OUTBF) ((ushort*)Cout)[(size_t)m * Nd + n] = f2bf(v);
        else       ((float*)Cout)[(size_t)m * Nd + n] = v;
      }
}

// ---------------- fused MFMA attention per (cluster, head) ----------------
__global__ __launch_bounds__(256) void attn_kernel(const ushort* __restrict__ Pq,
                                                   const ushort* __restrict__ Pkv,
                                                   const unsigned* __restrict__ adjw,
                                                   const float* __restrict__ e01,
                                                   const float* __restrict__ cosT,
                                                   const float* __restrict__ sinT,
                                                   ushort* __restrict__ AO) {
  __shared__ ushort Qb[128 * 64];
  __shared__ ushort Kb[128 * 64];
  __shared__ ushort VT[64 * 128];
  __shared__ ushort Pl[128 * 128];
  __shared__ unsigned adjL[512];
  __shared__ float e0s[64], e1s[64], qe0L[128], qe1L[128], sL[128];

  int t = threadIdx.x, w = t >> 6, l = t & 63;
  int kc = blockIdx.x >> 3, h = blockIdx.x & 7;

  const ushort* qg = Pq + (size_t)kc * 128 * INNERD + h * DD;
  const ushort* kg = Pkv + (size_t)kc * 128 * (2 * INNERD) + h * DD;
  const ushort* vg = kg + INNERD;

  // stage Q,K (chunk-swizzled), V transposed+swizzled
  for (int c = t; c < 1024; c += 256) {
    int r = c >> 3, ch = c & 7;
    uint4 qv = *(const uint4*)&qg[(size_t)r * INNERD + ch * 8];
    *(uint4*)&Qb[r * 64 + ((ch ^ (r & 7)) << 3)] = qv;
    uint4 kv = *(const uint4*)&kg[(size_t)r * (2 * INNERD) + ch * 8];
    *(uint4*)&Kb[r * 64 + ((ch ^ (r & 7)) << 3)] = kv;
    uint4 vv = *(const uint4*)&vg[(size_t)r * (2 * INNERD) + ch * 8];
    const ushort* vp = (const ushort*)&vv;
#pragma unroll
    for (int e = 0; e < 8; ++e) {
      int d = ch * 8 + e;
      VT[d * 128 + (((r >> 3) ^ (d & 7)) << 3) + (r & 7)] = vp[e];
    }
  }
  for (int f = t; f < 512; f += 256) adjL[f] = adjw[kc * 512 + f];
  if (t < 64) { e0s[t] = e01[h * DD + t]; e1s[t] = e01[512 + h * DD + t]; }
  __syncthreads();

  // rotary in-place on Qb, Kb (pairs d=2p,2p+1 share a dword)
  for (int f = t; f < 8192; f += 256) {
    int isk = f >> 12;
    int idx = f & 4095;
    int r = idx >> 5, p = idx & 31;
    float cv = cosT[p * 128 + r], sv = sinT[p * 128 + r];
    ushort* base = isk ? Kb : Qb;
    int d0 = 2 * p;
    int off = r * 64 + (((d0 >> 3) ^ (r & 7)) << 3) + (d0 & 7);
    unsigned u = *(unsigned*)&base[off];
    float a = bf2f((ushort)(u & 0xFFFF)), b = bf2f((ushort)(u >> 16));
    float na = a * cv - b * sv, nb = b * cv + a * sv;
    *(unsigned*)&base[off] = (unsigned)f2bf(na) | ((unsigned)f2bf(nb) << 16);
  }
  __syncthreads();

  // per-row q·e0, q·e1 (on rotated q, matching reference order)
  if (t < 128) {
    float a0 = 0.f, a1 = 0.f;
    for (int d = 0; d < 64; ++d) {
      float qv = bf2f(Qb[t * 64 + (((d >> 3) ^ (t & 7)) << 3) + (d & 7)]);
      a0 += qv * e0s[d]; a1 += qv * e1s[d];
    }
    qe0L[t] = a0; qe1L[t] = a1;
  }
  __syncthreads();

  // ---- QK^T: wave w owns rows m0..m0+31 (2 row-tiles x 8 col-tiles) ----
  int m0 = w * 32;
  f32x4 s_acc[2][8];
#pragma unroll
  for (int mi = 0; mi < 2; ++mi)
#pragma unroll
    for (int nj = 0; nj < 8; ++nj) s_acc[mi][nj] = (f32x4){0.f, 0.f, 0.f, 0.f};

  short8 aF[2][2];
#pragma unroll
  for (int mi = 0; mi < 2; ++mi)
#pragma unroll
    for (int kk = 0; kk < 2; ++kk) {
      int row = m0 + mi * 16 + (l & 15);
      int ch = kk * 4 + (l >> 4);
      aF[mi][kk] = *(const short8*)&Qb[row * 64 + ((ch ^ (row & 7)) << 3)];
    }
#pragma unroll
  for (int nj = 0; nj < 8; ++nj) {
    int row = nj * 16 + (l & 15);
    short8 b0 = *(const short8*)&Kb[row * 64 + ((((l >> 4)) ^ (row & 7)) << 3)];
    short8 b1 = *(const short8*)&Kb[row * 64 + (((4 + (l >> 4)) ^ (row & 7)) << 3)];
#pragma unroll
    for (int mi = 0; mi < 2; ++mi) {
      s_acc[mi][nj] = __builtin_amdgcn_mfma_f32_16x16x32_bf16(aF[mi][0], b0, s_acc[mi][nj], 0, 0, 0);
      s_acc[mi][nj] = __builtin_amdgcn_mfma_f32_16x16x32_bf16(aF[mi][1], b1, s_acc[mi][nj], 0, 0, 0);
    }
  }

  // ---- bias + softmax fully in registers ----
  float mrow[2][4], ssum[2][4], sadj[2][4];
#pragma unroll
  for (int mi = 0; mi < 2; ++mi)
#pragma unroll
    for (int r = 0; r < 4; ++r) {
      int i = m0 + mi * 16 + ((l >> 4) << 2) + r;
      float q0 = qe0L[i], q1 = qe1L[i];
      unsigned w0 = adjL[i * 4 + 0], w1 = adjL[i * 4 + 1], w2 = adjL[i * 4 + 2], w3 = adjL[i * 4 + 3];
      float mx = -1e30f;
#pragma unroll
      for (int nj = 0; nj < 8; ++nj) {
        unsigned word = (nj >> 1) == 0 ? w0 : (nj >> 1) == 1 ? w1 : (nj >> 1) == 2 ? w2 : w3;
        unsigned bit = (word >> (((nj & 1) << 4) + (l & 15))) & 1u;
        float s = (s_acc[mi][nj][r] + (bit ? q1 : q0)) * 0.125f;
        s_acc[mi][nj][r] = s;
        mx = fmaxf(mx, s);
      }
      mrow[mi][r] = mx;
    }
#pragma unroll
  for (int o = 1; o < 16; o <<= 1)
#pragma unroll
    for (int mi = 0; mi < 2; ++mi)
#pragma unroll
      for (int r = 0; r < 4; ++r) mrow[mi][r] = fmaxf(mrow[mi][r], __shfl_xor(mrow[mi][r], o));
#pragma unroll
  for (int mi = 0; mi < 2; ++mi)
#pragma unroll
    for (int r = 0; r < 4; ++r) {
      float sum = 0.f;
#pragma unroll
      for (int nj = 0; nj < 8; ++nj) {
        float p = __expf(s_acc[mi][nj][r] - mrow[mi][r]);
        s_acc[mi][nj][r] = p;
        sum += p;
      }
      ssum[mi][r] = sum;
    }
#pragma unroll
  for (int o = 1; o < 16; o <<= 1)
#pragma unroll
    for (int mi = 0; mi < 2; ++mi)
#pragma unroll
      for (int r = 0; r < 4; ++r) ssum[mi][r] += __shfl_xor(ssum[mi][r], o);
#pragma unroll
  for (int mi = 0; mi < 2; ++mi)
#pragma unroll
    for (int r = 0; r < 4; ++r) {
      int i = m0 + mi * 16 + ((l >> 4) << 2) + r;
      unsigned w0 = adjL[i * 4 + 0], w1 = adjL[i * 4 + 1], w2 = adjL[i * 4 + 2], w3 = adjL[i * 4 + 3];
      float inv = 1.0f / ssum[mi][r];
      float sa = 0.f;
#pragma unroll
      for (int nj = 0; nj < 8; ++nj) {
        int j = nj * 16 + (l & 15);
        unsigned word = (nj >> 1) == 0 ? w0 : (nj >> 1) == 1 ? w1 : (nj >> 1) == 2 ? w2 : w3;
        unsigned bit = (word >> (((nj & 1) << 4) + (l & 15))) & 1u;
        float p = s_acc[mi][nj][r] * inv;
        if (bit) sa += p;
        Pl[i * 128 + (((j >> 3) ^ (i & 7)) << 3) + (j & 7)] = f2bf(p);
      }
      sadj[mi][r] = sa;
    }
#pragma unroll
  for (int o = 1; o < 16; o <<= 1)
#pragma unroll
    for (int mi = 0; mi < 2; ++mi)
#pragma unroll
      for (int r = 0; r < 4; ++r) sadj[mi][r] += __shfl_xor(sadj[mi][r], o);
  if ((l & 15) == 0) {
#pragma unroll
    for (int mi = 0; mi < 2; ++mi)
#pragma unroll
      for (int r = 0; r < 4; ++r) sL[m0 + mi * 16 + ((l >> 4) << 2) + r] = sadj[mi][r];
  }
  __syncthreads();

  // ---- PV: O = P @ V  (2 row-tiles x 4 d-tiles, K=128 in 4 slices) ----
  f32x4 o_acc[2][4];
#pragma unroll
  for (int mi = 0; mi < 2; ++mi)
#pragma unroll
    for (int nj = 0; nj < 4; ++nj) o_acc[mi][nj] = (f32x4){0.f, 0.f, 0.f, 0.f};
#pragma unroll
  for (int kk = 0; kk < 4; ++kk) {
    short8 pa[2];
#pragma unroll
    for (int mi = 0; mi < 2; ++mi) {
      int row = m0 + mi * 16 + (l & 15);
      int ch = kk * 4 + (l >> 4);
      pa[mi] = *(const short8*)&Pl[row * 128 + ((ch ^ (row & 7)) << 3)];
    }
#pragma unroll
    for (int nj = 0; nj < 4; ++nj) {
      int vrow = nj * 16 + (l & 15);
      int ch = kk * 4 + (l >> 4);
      short8 vf = *(const short8*)&VT[vrow * 128 + ((ch ^ (vrow & 7)) << 3)];
#pragma unroll
      for (int mi = 0; mi < 2; ++mi)
        o_acc[mi][nj] = __builtin_amdgcn_mfma_f32_16x16x32_bf16(pa[mi], vf, o_acc[mi][nj], 0, 0, 0);
    }
  }
#pragma unroll
  for (int mi = 0; mi < 2; ++mi)
#pragma unroll
    for (int nj = 0; nj < 4; ++nj)
#pragma unroll
      for (int r = 0; r < 4; ++r) {
        int i = m0 + mi * 16 + ((l >> 4) << 2) + r;
        int d = nj * 16 + (l & 15);
        float s = sL[i];
        float v = o_acc[mi][nj][r] + e0s[d] * (1.0f - s) + e1s[d] * s;
        AO[(size_t)(kc * 128 + i) * INNERD + h * DD + d] = f2bf(v);
      }
}

// ---------------- gated residual (wave per row) ----------------
__global__ __launch_bounds__(256) void gated_res_kernel(const float* __restrict__ xn,
                                                        const float* __restrict__ resbuf,
                                                        const int* __restrict__ cl,
                                                        const float* __restrict__ Wg,
                                                        float* __restrict__ out) {
  int row = blockIdx.x * 4 + (threadIdx.x >> 6);
  int lane = threadIdx.x & 63;
  int src = cl ? cl[row] : row;
  float2 a = *(const float2*)(xn + (size_t)row * CC + lane * 2);
  float2 r = *(const float2*)(resbuf + (size_t)src * CC + lane * 2);
  int c = lane * 2;
  float w0a = Wg[c] + Wg[256 + c], w0b = Wg[c + 1] + Wg[256 + c + 1];
  float w1a = Wg[128 + c] - Wg[256 + c], w1b = Wg[128 + c + 1] - Wg[256 + c + 1];
  float dot = a.x * w0a + a.y * w0b + r.x * w1a + r.y * w1b;
#pragma unroll
  for (int o = 32; o; o >>= 1) dot += __shfl_xor(dot, o);
  float g = 1.0f / (1.0f + __expf(-dot));
  float2 o2;
  o2.x = a.x * g + r.x * (1.0f - g);
  o2.y = a.y * g + r.y * (1.0f - g);
  *(float2*)(out + (size_t)row * CC + lane * 2) = o2;
}

// ---------------- final: gated residual 2 + add into x ----------------
__global__ __launch_bounds__(256) void final_kernel(const float* __restrict__ ff,
                                                    const float* __restrict__ n1,
                                                    const float* __restrict__ x,
                                                    const int* __restrict__ cl,
                                                    const float* __restrict__ Wg,
                                                    float* __restrict__ out) {
  int row = blockIdx.x * 4 + (threadIdx.x >> 6);
  int lane = threadIdx.x & 63;
  int src = cl[row];
  float2 a = *(const float2*)(ff + (size_t)row * CC + lane * 2);
  float2 r = *(const float2*)(n1 + (size_t)row * CC + lane * 2);
  int c = lane * 2;
  float w0a = Wg[c] + Wg[256 + c], w0b = Wg[c + 1] + Wg[256 + c + 1];
  float w1a = Wg[128 + c] - Wg[256 + c], w1b = Wg[128 + c + 1] - Wg[256 + c + 1];
  float dot = a.x * w0a + a.y * w0b + r.x * w1a + r.y * w1b;
#pragma unroll
  for (int o = 32; o; o >>= 1) dot += __shfl_xor(dot, o);
  float g = 1.0f / (1.0f + __expf(-dot));
  float2 xv = *(const float2*)(x + (size_t)src * CC + lane * 2);
  float2 o2;
  o2.x = xv.x + a.x * g + r.x * (1.0f - g);
  o2.y = xv.y + a.y * g + r.y * (1.0f - g);
  *(float2*)(out + (size_t)src * CC + lane * 2) = o2;
}

extern "C" void kernel_launch(void* const* d_in, const int* in_sizes, int n_in,
                              void* d_out, int out_size, void* d_ws, size_t ws_size,
                              hipStream_t stream) {
  const float* x       = (const float*)d_in[0];
  const int*   edge    = (const int*)d_in[1];
  const int*   clusters= (const int*)d_in[2];
  const float* adj_emb = (const float*)d_in[3];
  const float* ln1_g   = (const float*)d_in[4];
  const float* ln1_b   = (const float*)d_in[5];
  const float* Wq      = (const float*)d_in[6];
  const float* bq      = (const float*)d_in[7];
  const float* Wkv     = (const float*)d_in[8];
  const float* bkv     = (const float*)d_in[9];
  const float* We      = (const float*)d_in[10];
  const float* be      = (const float*)d_in[11];
  const float* Wo      = (const float*)d_in[12];
  const float* bo      = (const float*)d_in[13];
  const float* gate1   = (const float*)d_in[14];
  const float* ln2_g   = (const float*)d_in[15];
  const float* ln2_b   = (const float*)d_in[16];
  const float* W1      = (const float*)d_in[17];
  const float* b1      = (const float*)d_in[18];
  const float* W2      = (const float*)d_in[19];
  const float* b2      = (const float*)d_in[20];
  const float* gate2   = (const float*)d_in[21];

  char* wsb = (char*)d_ws;
  unsigned* adjw = (unsigned*)wsb;                    // 64 KB
  float* e01  = (float*)(wsb + 65536);                // 4 KB
  float* cosT = (float*)(wsb + 69632);                // 16 KB
  float* sinT = (float*)(wsb + 86016);                // 16 KB
  ushort* WqT  = (ushort*)(wsb + 102400);             // 128 KB
  ushort* WkvT = (ushort*)(wsb + 233472);             // 256 KB
  ushort* WoT  = (ushort*)(wsb + 495616);             // 128 KB
  ushort* W1T  = (ushort*)(wsb + 626688);             // 128 KB
  ushort* W2T  = (ushort*)(wsb + 757760);             // 128 KB
  ushort* y    = (ushort*)(wsb + 888832);             // 1 MB  (bf16 4096x128)
  ushort* Pq   = (ushort*)(wsb + 1937408);            // 4 MB  (bf16 4096x512)
  ushort* Pkv  = (ushort*)(wsb + 6131712);            // 8 MB  (bf16 4096x1024)
  ushort* AO   = (ushort*)(wsb + 14520320);           // 4 MB  (bf16 4096x512)
  float* t1    = (float*)(wsb + 18714624);            // 2 MB
  float* n1    = (float*)(wsb + 20811776);            // 2 MB
  ushort* y2  = y;    // reuse (y dead after Q/KV GEMMs)
  ushort* ffh = Pq;   // reuse (Pq dead after attention)
  float*  ffo = t1;   // reuse (t1 dead after gated1)

  hipMemsetAsync(adjw, 0, 65536, stream);
  build_adj_kernel<<<EE / 256, 256, 0, stream>>>(edge, adjw);
  prep_kernel<<<20, 256, 0, stream>>>(adj_emb, We, be, e01, cosT, sinT);
  wconv_kernel<<<1536, 256, 0, stream>>>(Wq, Wkv, Wo, W1, W2, WqT, WkvT, WoT, W1T, W2T);
  ln_kernel<<<NNODES / 4, 256, 0, stream>>>(x, clusters, ln1_g, ln1_b, y);
  gemm_bf16_kernel<0, 1><<<dim3(4, 32), 256, 0, stream>>>(y, WqT, bq, Pq, 128, 512);
  gemm_bf16_kernel<0, 1><<<dim3(8, 32), 256, 0, stream>>>(y, WkvT, bkv, Pkv, 128, 1024);
  attn_kernel<<<KCL * HH, 256, 0, stream>>>(Pq, Pkv, adjw, e01, cosT, sinT, AO);
  gemm_bf16_kernel<0, 0><<<dim3(1, 32), 256, 0, stream>>>(AO, WoT, bo, t1, 512, 128);
  gated_res_kernel<<<NNODES / 4, 256, 0, stream>>>(t1, x, clusters, gate1, n1);
  ln_kernel<<<NNODES / 4, 256, 0, stream>>>(n1, nullptr, ln2_g, ln2_b, y2);
  gemm_bf16_kernel<1, 1><<<dim3(4, 32), 256, 0, stream>>>(y2, W1T, b1, ffh, 128, 512);
  gemm_bf16_kernel<0, 0><<<dim3(1, 32), 256, 0, stream>>>(ffh, W2T, b2, ffo, 512, 128);
  final_kernel<<<NNODES / 4, 256, 0, stream>>>(ffo, n1, x, clusters, gate2, (float*)d_out);
}

// Round 3
// 91.555 us; speedup vs baseline: 1.8832x; 1.1864x over previous
//
#include <hip/hip_runtime.h>
#include <math.h>

#define NNODES 4096
#define CC     128
#define KCL    32
#define MM     128
#define EE     65536
#define HH     8
#define DD     64
#define INNERD 512

typedef __attribute__((ext_vector_type(8))) short short8;
typedef __attribute__((ext_vector_type(4))) float f32x4;

__device__ __forceinline__ float bf2f(ushort u) { return __uint_as_float(((unsigned)u) << 16); }
__device__ __forceinline__ ushort f2bf(float f) {
  unsigned b = __float_as_uint(f);
  return (ushort)((b + 0x7FFFu + ((b >> 16) & 1u)) >> 16);
}

// ---------------- preprocessing: weight transpose + e01 + rotary tables + adj zero ----
__global__ __launch_bounds__(256) void pre_kernel(const float* __restrict__ Wq,
                                                  const float* __restrict__ Wkv,
                                                  const float* __restrict__ Wo,
                                                  const float* __restrict__ W1,
                                                  const float* __restrict__ W2,
                                                  const float* __restrict__ adj_emb,
                                                  const float* __restrict__ We,
                                                  const float* __restrict__ be,
                                                  ushort* __restrict__ WqkvT,
                                                  ushort* __restrict__ WoT,
                                                  ushort* __restrict__ W1T,
                                                  ushort* __restrict__ W2T,
                                                  float* __restrict__ e01,
                                                  float* __restrict__ cosF,
                                                  float* __restrict__ sinF,
                                                  unsigned* __restrict__ adjw) {
  int bid = blockIdx.x, t = threadIdx.x;
  if (bid < 1536) {
    int g = bid * 256 + t;
    if (g < 65536) {               // Wq [128,512] -> rows 0..511 of WqkvT[1536][128]
      int n = g >> 7, k = g & 127;
      WqkvT[n * 128 + k] = f2bf(Wq[(size_t)k * 512 + n]);
    } else if (g < 196608) {       // Wkv [128,1024] -> rows 512..1535
      int idx = g - 65536, n = idx >> 7, k = idx & 127;
      WqkvT[(512 + n) * 128 + k] = f2bf(Wkv[(size_t)k * 1024 + n]);
    } else if (g < 262144) {       // Wo [512,128] -> WoT[128][512]
      int idx = g - 196608, n = idx >> 9, k = idx & 511;
      WoT[n * 512 + k] = f2bf(Wo[(size_t)k * 128 + n]);
    } else if (g < 327680) {       // W1 [128,512] -> W1T[512][128]
      int idx = g - 262144, n = idx >> 7, k = idx & 127;
      W1T[n * 128 + k] = f2bf(W1[(size_t)k * 512 + n]);
    } else {                       // W2 [512,128] -> W2T[128][512]
      int idx = g - 327680, n = idx >> 9, k = idx & 511;
      W2T[n * 512 + k] = f2bf(W2[(size_t)k * 128 + n]);
    }
  } else if (bid < 1540) {         // e01
    int idx = (bid - 1536) * 256 + t;  // 0..1023
    int which = idx >> 9, col = idx & 511;
    float a = 0.f;
    for (int c = 0; c < CC; ++c) a += adj_emb[which * CC + c] * We[(size_t)c * INNERD + col];
    e01[idx] = a + be[col];
  } else if (bid < 1548) {         // rotary tables [i][d], i in 0..127, d in 0..63
#pragma unroll
    for (int e = 0; e < 4; ++e) {
      int idx = ((bid - 1540) * 256 + t) * 4 + e;  // 0..8191
      int i = idx >> 6, d = idx & 63, p = d >> 1;
      float inv = exp2f(-(float)p * (13.287712379549449f / 32.0f)); // 10000^(-p/32)
      float ang = (float)i * inv;
      cosF[idx] = cosf(ang);
      sinF[idx] = sinf(ang);
    }
  } else {                         // zero adjw (16384 words)
    int base = ((bid - 1548) * 256 + t) * 16;
#pragma unroll
    for (int e = 0; e < 16; ++e) adjw[base + e] = 0u;
  }
}

// ---------------- adjacency bitmask ----------------
__global__ __launch_bounds__(256) void build_adj_kernel(const int* __restrict__ ei,
                                                        unsigned* __restrict__ adjw) {
  int e = blockIdx.x * 256 + threadIdx.x;
  if (e >= EE) return;
  int s = ei[e], d = ei[EE + e];
  int cs = s >> 7, cd = d >> 7;
  if (cs == cd) {
    int flat = cs * (MM * MM) + (s & 127) * MM + (d & 127);
    atomicOr(adjw + (flat >> 5), 1u << (flat & 31));
  }
}

// ---------------- LayerNorm (wave per row) -> bf16 ----------------
__global__ __launch_bounds__(256) void ln_kernel(const float* __restrict__ in,
                                                 const int* __restrict__ cl,
                                                 const float* __restrict__ gg,
                                                 const float* __restrict__ bb,
                                                 ushort* __restrict__ y) {
  int row = blockIdx.x * 4 + (threadIdx.x >> 6);
  int lane = threadIdx.x & 63;
  int src = cl ? cl[row] : row;
  const float* p = in + (size_t)src * CC;
  float2 v = *(const float2*)(p + lane * 2);
  float s = v.x + v.y, q = v.x * v.x + v.y * v.y;
#pragma unroll
  for (int o = 32; o; o >>= 1) { s += __shfl_xor(s, o); q += __shfl_xor(q, o); }
  float mu = s * (1.0f / CC);
  float var = q * (1.0f / CC) - mu * mu;
  float rs = rsqrtf(var + 1e-5f);
  float2 g2 = *(const float2*)(gg + lane * 2);
  float2 b2 = *(const float2*)(bb + lane * 2);
  float ox = (v.x - mu) * rs * g2.x + b2.x;
  float oy = (v.y - mu) * rs * g2.y + b2.y;
  *(unsigned*)&y[(size_t)row * CC + lane * 2] = (unsigned)f2bf(ox) | ((unsigned)f2bf(oy) << 16);
}

// ---------------- QKV GEMM with fused rotary: P = [q|k|v], rotary on cols<1024 ------
// A = y [4096][128] bf16, BT = WqkvT [1536][128] bf16. 128x128 tile, BK=32.
__global__ __launch_bounds__(256) void qkv_gemm_kernel(const ushort* __restrict__ A,
                                                       const ushort* __restrict__ BT,
                                                       const float* __restrict__ bq,
                                                       const float* __restrict__ bkv,
                                                       const float* __restrict__ cosF,
                                                       const float* __restrict__ sinF,
                                                       ushort* __restrict__ P) {
  __shared__ __align__(16) ushort Ab[128 * 32];
  __shared__ __align__(16) ushort Bb[128 * 32];
  int t = threadIdx.x;
  int w = t >> 6, l = t & 63;
  int n0 = blockIdx.x * 128, m0 = blockIdx.y * 128;
  int wr = (w >> 1) * 64, wc = (w & 1) * 64;
  f32x4 acc[4][4];
#pragma unroll
  for (int mi = 0; mi < 4; ++mi)
#pragma unroll
    for (int nj = 0; nj < 4; ++nj) acc[mi][nj] = (f32x4){0.f, 0.f, 0.f, 0.f};

  for (int k0 = 0; k0 < 128; k0 += 32) {
#pragma unroll
    for (int i = 0; i < 2; ++i) {
      int c = t + i * 256;
      int r = c >> 2, kc = c & 3;
      *(uint4*)&Ab[r * 32 + kc * 8] = *(const uint4*)&A[(size_t)(m0 + r) * 128 + k0 + kc * 8];
      *(uint4*)&Bb[r * 32 + kc * 8] = *(const uint4*)&BT[(size_t)(n0 + r) * 128 + k0 + kc * 8];
    }
    __syncthreads();
    short8 aF[4], bF[4];
#pragma unroll
    for (int mi = 0; mi < 4; ++mi) aF[mi] = *(const short8*)&Ab[(wr + mi * 16 + (l & 15)) * 32 + (l >> 4) * 8];
#pragma unroll
    for (int nj = 0; nj < 4; ++nj) bF[nj] = *(const short8*)&Bb[(wc + nj * 16 + (l & 15)) * 32 + (l >> 4) * 8];
#pragma unroll
    for (int mi = 0; mi < 4; ++mi)
#pragma unroll
      for (int nj = 0; nj < 4; ++nj)
        acc[mi][nj] = __builtin_amdgcn_mfma_f32_16x16x32_bf16(aF[mi], bF[nj], acc[mi][nj], 0, 0, 0);
    __syncthreads();
  }
#pragma unroll
  for (int mi = 0; mi < 4; ++mi)
#pragma unroll
    for (int nj = 0; nj < 4; ++nj)
#pragma unroll
      for (int r = 0; r < 4; ++r) {
        int m = m0 + wr + mi * 16 + ((l >> 4) << 2) + r;
        int n = n0 + wc + nj * 16 + (l & 15);
        float bias = n < 512 ? bq[n] : bkv[n - 512];
        float v = acc[mi][nj][r] + bias;
        float partner = __shfl_xor(v, 1);
        if (n < 1024) {
          int d = n & 63, i = m & 127;
          float cv = cosF[i * 64 + d], sv = sinF[i * 64 + d];
          v = (n & 1) ? (v * cv + partner * sv) : (v * cv - partner * sv);
        }
        P[(size_t)m * 1536 + n] = f2bf(v);
      }
}

// ---------------- fused MFMA attention per (cluster, head), 512 threads ----------------
__global__ __launch_bounds__(512) void attn_kernel(const ushort* __restrict__ P,
                                                   const unsigned* __restrict__ adjw,
                                                   const float* __restrict__ e01,
                                                   ushort* __restrict__ AO) {
  __shared__ __align__(16) ushort QKP[2 * 128 * 64];  // Qb | Kb ; Pl overlays both
  __shared__ __align__(16) ushort VT[64 * 128];
  __shared__ unsigned adjL[512];
  __shared__ float e0s[64], e1s[64], qe0L[128], qe1L[128], sL[128];
  ushort* Qb = QKP;
  ushort* Kb = QKP + 8192;
  ushort* Pl = QKP;

  int t = threadIdx.x, w = t >> 6, l = t & 63;
  int kc = blockIdx.x >> 3, h = blockIdx.x & 7;

  const ushort* qg = P + (size_t)kc * 128 * 1536 + h * DD;

  // stage Q,K (chunk-swizzled), V transposed+swizzled
  for (int c = t; c < 1024; c += 512) {
    int r = c >> 3, ch = c & 7;
    uint4 qv = *(const uint4*)&qg[(size_t)r * 1536 + ch * 8];
    *(uint4*)&Qb[r * 64 + ((ch ^ (r & 7)) << 3)] = qv;
    uint4 kv = *(const uint4*)&qg[(size_t)r * 1536 + 512 + ch * 8];
    *(uint4*)&Kb[r * 64 + ((ch ^ (r & 7)) << 3)] = kv;
    uint4 vv = *(const uint4*)&qg[(size_t)r * 1536 + 1024 + ch * 8];
    const ushort* vp = (const ushort*)&vv;
#pragma unroll
    for (int e = 0; e < 8; ++e) {
      int d = ch * 8 + e;
      VT[d * 128 + (((r >> 3) ^ (d & 7)) << 3) + (r & 7)] = vp[e];
    }
  }
  adjL[t & 511] = adjw[kc * 512 + (t & 511)];
  if (t < 64) { e0s[t] = e01[h * DD + t]; e1s[t] = e01[512 + h * DD + t]; }
  __syncthreads();

  // per-row q·e0, q·e1 on rotated q (512 threads: 128 rows x 4 parts)
  {
    int row = t >> 2, part = t & 3;
    float a0 = 0.f, a1 = 0.f;
#pragma unroll
    for (int dd = 0; dd < 16; ++dd) {
      int d = part * 16 + dd;
      float qv = bf2f(Qb[row * 64 + (((d >> 3) ^ (row & 7)) << 3) + (d & 7)]);
      a0 += qv * e0s[d]; a1 += qv * e1s[d];
    }
    a0 += __shfl_xor(a0, 1); a0 += __shfl_xor(a0, 2);
    a1 += __shfl_xor(a1, 1); a1 += __shfl_xor(a1, 2);
    if (part == 0) { qe0L[row] = a0; qe1L[row] = a1; }
  }
  __syncthreads();

  // ---- QK^T: wave w owns row-tile m0 = w*16 (1 x 8 col-tiles) ----
  int m0 = w * 16;
  f32x4 s_acc[8];
#pragma unroll
  for (int nj = 0; nj < 8; ++nj) s_acc[nj] = (f32x4){0.f, 0.f, 0.f, 0.f};
  {
    int arow = m0 + (l & 15);
    short8 aF0 = *(const short8*)&Qb[arow * 64 + ((((l >> 4)) ^ (arow & 7)) << 3)];
    short8 aF1 = *(const short8*)&Qb[arow * 64 + (((4 + (l >> 4)) ^ (arow & 7)) << 3)];
#pragma unroll
    for (int nj = 0; nj < 8; ++nj) {
      int brow = nj * 16 + (l & 15);
      short8 b0 = *(const short8*)&Kb[brow * 64 + ((((l >> 4)) ^ (brow & 7)) << 3)];
      short8 b1 = *(const short8*)&Kb[brow * 64 + (((4 + (l >> 4)) ^ (brow & 7)) << 3)];
      s_acc[nj] = __builtin_amdgcn_mfma_f32_16x16x32_bf16(aF0, b0, s_acc[nj], 0, 0, 0);
      s_acc[nj] = __builtin_amdgcn_mfma_f32_16x16x32_bf16(aF1, b1, s_acc[nj], 0, 0, 0);
    }
  }

  // ---- bias + softmax in registers (lane covers rows m0+(l>>4)*4+r, col j=nj*16+(l&15)) ----
  float mrow[4], ssum[4], sadj[4];
#pragma unroll
  for (int r = 0; r < 4; ++r) {
    int i = m0 + ((l >> 4) << 2) + r;
    float q0 = qe0L[i], q1 = qe1L[i];
    unsigned w0 = adjL[i * 4 + 0], w1 = adjL[i * 4 + 1], w2 = adjL[i * 4 + 2], w3 = adjL[i * 4 + 3];
    float mx = -1e30f;
#pragma unroll
    for (int nj = 0; nj < 8; ++nj) {
      unsigned word = (nj >> 1) == 0 ? w0 : (nj >> 1) == 1 ? w1 : (nj >> 1) == 2 ? w2 : w3;
      unsigned bit = (word >> (((nj & 1) << 4) + (l & 15))) & 1u;
      float s = (s_acc[nj][r] + (bit ? q1 : q0)) * 0.125f;
      s_acc[nj][r] = s;
      mx = fmaxf(mx, s);
    }
    mrow[r] = mx;
  }
#pragma unroll
  for (int o = 1; o < 16; o <<= 1)
#pragma unroll
    for (int r = 0; r < 4; ++r) mrow[r] = fmaxf(mrow[r], __shfl_xor(mrow[r], o));
#pragma unroll
  for (int r = 0; r < 4; ++r) {
    float sum = 0.f;
#pragma unroll
    for (int nj = 0; nj < 8; ++nj) {
      float p = __expf(s_acc[nj][r] - mrow[r]);
      s_acc[nj][r] = p;
      sum += p;
    }
    ssum[r] = sum;
  }
#pragma unroll
  for (int o = 1; o < 16; o <<= 1)
#pragma unroll
    for (int r = 0; r < 4; ++r) ssum[r] += __shfl_xor(ssum[r], o);
#pragma unroll
  for (int r = 0; r < 4; ++r) {
    int i = m0 + ((l >> 4) << 2) + r;
    unsigned w0 = adjL[i * 4 + 0], w1 = adjL[i * 4 + 1], w2 = adjL[i * 4 + 2], w3 = adjL[i * 4 + 3];
    float inv = 1.0f / ssum[r];
    float sa = 0.f;
#pragma unroll
    for (int nj = 0; nj < 8; ++nj) {
      unsigned word = (nj >> 1) == 0 ? w0 : (nj >> 1) == 1 ? w1 : (nj >> 1) == 2 ? w2 : w3;
      unsigned bit = (word >> (((nj & 1) << 4) + (l & 15))) & 1u;
      float p = s_acc[nj][r] * inv;
      s_acc[nj][r] = p;
      if (bit) sa += p;
    }
    sadj[r] = sa;
  }
#pragma unroll
  for (int o = 1; o < 16; o <<= 1)
#pragma unroll
    for (int r = 0; r < 4; ++r) sadj[r] += __shfl_xor(sadj[r], o);

  __syncthreads();  // all QK^T / qe0 reads of Qb,Kb complete -> safe to overlay Pl

#pragma unroll
  for (int r = 0; r < 4; ++r) {
    int i = m0 + ((l >> 4) << 2) + r;
#pragma unroll
    for (int nj = 0; nj < 8; ++nj) {
      int j = nj * 16 + (l & 15);
      Pl[i * 128 + (((j >> 3) ^ (i & 7)) << 3) + (j & 7)] = f2bf(s_acc[nj][r]);
    }
    if ((l & 15) == 0) sL[i] = sadj[r];
  }
  __syncthreads();

  // ---- PV: O = P @ V (1 row-tile x 4 d-tiles, K=128 in 4 slices) ----
  f32x4 o_acc[4];
#pragma unroll
  for (int nj = 0; nj < 4; ++nj) o_acc[nj] = (f32x4){0.f, 0.f, 0.f, 0.f};
#pragma unroll
  for (int kk = 0; kk < 4; ++kk) {
    int prow = m0 + (l & 15);
    int ch = kk * 4 + (l >> 4);
    short8 pa = *(const short8*)&Pl[prow * 128 + ((ch ^ (prow & 7)) << 3)];
#pragma unroll
    for (int nj = 0; nj < 4; ++nj) {
      int vrow = nj * 16 + (l & 15);
      short8 vf = *(const short8*)&VT[vrow * 128 + ((ch ^ (vrow & 7)) << 3)];
      o_acc[nj] = __builtin_amdgcn_mfma_f32_16x16x32_bf16(pa, vf, o_acc[nj], 0, 0, 0);
    }
  }
#pragma unroll
  for (int nj = 0; nj < 4; ++nj)
#pragma unroll
    for (int r = 0; r < 4; ++r) {
      int i = m0 + ((l >> 4) << 2) + r;
      int d = nj * 16 + (l & 15);
      float s = sL[i];
      float v = o_acc[nj][r] + e0s[d] * (1.0f - s) + e1s[d] * s;
      AO[(size_t)(kc * 128 + i) * INNERD + h * DD + d] = f2bf(v);
    }
}

// ---------------- Wo GEMM + gate1 + LN2 : M-tile 64, N=128 full ----------------
__global__ __launch_bounds__(256) void wo_gate_kernel(const ushort* __restrict__ A,
                                                      const ushort* __restrict__ BT,
                                                      const float* __restrict__ bo,
                                                      const float* __restrict__ x,
                                                      const int* __restrict__ cl,
                                                      const float* __restrict__ g1,
                                                      const float* __restrict__ lng,
                                                      const float* __restrict__ lnb,
                                                      float* __restrict__ n1,
                                                      ushort* __restrict__ y2) {
  __shared__ __align__(16) ushort Ab[64 * 32];
  __shared__ __align__(16) ushort Bb[128 * 32];
  __shared__ float tld[64][132];
  __shared__ float w0g[128], w1g[128], lnGs[128], lnBs[128];
  int t = threadIdx.x, w = t >> 6, l = t & 63;
  int m0 = blockIdx.x * 64;
  int wr = (w >> 1) * 32, wc = (w & 1) * 64;
  if (t < 128) { w0g[t] = g1[t] + g1[256 + t]; w1g[t] = g1[128 + t] - g1[256 + t]; }
  else { lnGs[t - 128] = lng[t - 128]; lnBs[t - 128] = lnb[t - 128]; }
  f32x4 acc[2][4];
#pragma unroll
  for (int mi = 0; mi < 2; ++mi)
#pragma unroll
    for (int nj = 0; nj < 4; ++nj) acc[mi][nj] = (f32x4){0.f, 0.f, 0.f, 0.f};
  for (int k0 = 0; k0 < 512; k0 += 32) {
    {
      int r = t >> 2, kc = t & 3;
      *(uint4*)&Ab[r * 32 + kc * 8] = *(const uint4*)&A[(size_t)(m0 + r) * 512 + k0 + kc * 8];
    }
#pragma unroll
    for (int i = 0; i < 2; ++i) {
      int c = t + i * 256;
      int r = c >> 2, kc = c & 3;
      *(uint4*)&Bb[r * 32 + kc * 8] = *(const uint4*)&BT[(size_t)r * 512 + k0 + kc * 8];
    }
    __syncthreads();
    short8 aF[2], bF[4];
#pragma unroll
    for (int mi = 0; mi < 2; ++mi) aF[mi] = *(const short8*)&Ab[(wr + mi * 16 + (l & 15)) * 32 + (l >> 4) * 8];
#pragma unroll
    for (int nj = 0; nj < 4; ++nj) bF[nj] = *(const short8*)&Bb[(wc + nj * 16 + (l & 15)) * 32 + (l >> 4) * 8];
#pragma unroll
    for (int mi = 0; mi < 2; ++mi)
#pragma unroll
      for (int nj = 0; nj < 4; ++nj)
        acc[mi][nj] = __builtin_amdgcn_mfma_f32_16x16x32_bf16(aF[mi], bF[nj], acc[mi][nj], 0, 0, 0);
    __syncthreads();
  }
#pragma unroll
  for (int mi = 0; mi < 2; ++mi)
#pragma unroll
    for (int nj = 0; nj < 4; ++nj)
#pragma unroll
      for (int r = 0; r < 4; ++r) {
        int row = wr + mi * 16 + ((l >> 4) << 2) + r;
        int col = wc + nj * 16 + (l & 15);
        tld[row][col] = acc[mi][nj][r] + bo[col];
      }
  __syncthreads();
  // gate + LN: 4 threads per row
  {
    int row = t >> 2, part = t & 3;
    int src = cl[m0 + row];
    const float* xr = x + (size_t)src * CC + part * 32;
    float dot = 0.f;
#pragma unroll
    for (int j = 0; j < 32; ++j) {
      int c = part * 32 + j;
      dot += tld[row][c] * w0g[c] + xr[j] * w1g[c];
    }
    dot += __shfl_xor(dot, 1); dot += __shfl_xor(dot, 2);
    float g = 1.0f / (1.0f + __expf(-dot));
    float s = 0.f, q = 0.f;
#pragma unroll
    for (int j = 0; j < 32; ++j) {
      int c = part * 32 + j;
      float nv = tld[row][c] * g + xr[j] * (1.0f - g);
      tld[row][c] = nv;
      n1[(size_t)(m0 + row) * CC + c] = nv;
      s += nv; q += nv * nv;
    }
    s += __shfl_xor(s, 1); s += __shfl_xor(s, 2);
    q += __shfl_xor(q, 1); q += __shfl_xor(q, 2);
    float mu = s * (1.0f / CC);
    float var = q * (1.0f / CC) - mu * mu;
    float rs = rsqrtf(var + 1e-5f);
#pragma unroll
    for (int j = 0; j < 32; ++j) {
      int c = part * 32 + j;
      y2[(size_t)(m0 + row) * CC + c] = f2bf((tld[row][c] - mu) * rs * lnGs[c] + lnBs[c]);
    }
  }
}

// ---------------- W1 GEMM + exact GELU -> ffh bf16 ----------------
__global__ __launch_bounds__(256) void w1_gemm_kernel(const ushort* __restrict__ A,
                                                      const ushort* __restrict__ BT,
                                                      const float* __restrict__ bias,
                                                      ushort* __restrict__ Cout) {
  __shared__ __align__(16) ushort Ab[128 * 32];
  __shared__ __align__(16) ushort Bb[128 * 32];
  int t = threadIdx.x;
  int w = t >> 6, l = t & 63;
  int n0 = blockIdx.x * 128, m0 = blockIdx.y * 128;
  int wr = (w >> 1) * 64, wc = (w & 1) * 64;
  f32x4 acc[4][4];
#pragma unroll
  for (int mi = 0; mi < 4; ++mi)
#pragma unroll
    for (int nj = 0; nj < 4; ++nj) acc[mi][nj] = (f32x4){0.f, 0.f, 0.f, 0.f};
  for (int k0 = 0; k0 < 128; k0 += 32) {
#pragma unroll
    for (int i = 0; i < 2; ++i) {
      int c = t + i * 256;
      int r = c >> 2, kc = c & 3;
      *(uint4*)&Ab[r * 32 + kc * 8] = *(const uint4*)&A[(size_t)(m0 + r) * 128 + k0 + kc * 8];
      *(uint4*)&Bb[r * 32 + kc * 8] = *(const uint4*)&BT[(size_t)(n0 + r) * 128 + k0 + kc * 8];
    }
    __syncthreads();
    short8 aF[4], bF[4];
#pragma unroll
    for (int mi = 0; mi < 4; ++mi) aF[mi] = *(const short8*)&Ab[(wr + mi * 16 + (l & 15)) * 32 + (l >> 4) * 8];
#pragma unroll
    for (int nj = 0; nj < 4; ++nj) bF[nj] = *(const short8*)&Bb[(wc + nj * 16 + (l & 15)) * 32 + (l >> 4) * 8];
#pragma unroll
    for (int mi = 0; mi < 4; ++mi)
#pragma unroll
      for (int nj = 0; nj < 4; ++nj)
        acc[mi][nj] = __builtin_amdgcn_mfma_f32_16x16x32_bf16(aF[mi], bF[nj], acc[mi][nj], 0, 0, 0);
    __syncthreads();
  }
#pragma unroll
  for (int mi = 0; mi < 4; ++mi)
#pragma unroll
    for (int nj = 0; nj < 4; ++nj)
#pragma unroll
      for (int r = 0; r < 4; ++r) {
        int m = m0 + wr + mi * 16 + ((l >> 4) << 2) + r;
        int n = n0 + wc + nj * 16 + (l & 15);
        float v = acc[mi][nj][r] + bias[n];
        v = 0.5f * v * (1.0f + erff(v * 0.70710678118654752f));
        Cout[(size_t)m * 512 + n] = f2bf(v);
      }
}

// ---------------- W2 GEMM + gate2 + final add : M-tile 64 ----------------
__global__ __launch_bounds__(256) void w2_final_kernel(const ushort* __restrict__ A,
                                                       const ushort* __restrict__ BT,
                                                       const float* __restrict__ b2,
                                                       const float* __restrict__ n1,
                                                       const float* __restrict__ x,
                                                       const int* __restrict__ cl,
                                                       const float* __restrict__ g2,
                                                       float* __restrict__ out) {
  __shared__ __align__(16) ushort Ab[64 * 32];
  __shared__ __align__(16) ushort Bb[128 * 32];
  __shared__ float tld[64][132];
  __shared__ float w0g[128], w1g[128];
  int t = threadIdx.x, w = t >> 6, l = t & 63;
  int m0 = blockIdx.x * 64;
  int wr = (w >> 1) * 32, wc = (w & 1) * 64;
  if (t < 128) { w0g[t] = g2[t] + g2[256 + t]; w1g[t] = g2[128 + t] - g2[256 + t]; }
  f32x4 acc[2][4];
#pragma unroll
  for (int mi = 0; mi < 2; ++mi)
#pragma unroll
    for (int nj = 0; nj < 4; ++nj) acc[mi][nj] = (f32x4){0.f, 0.f, 0.f, 0.f};
  for (int k0 = 0; k0 < 512; k0 += 32) {
    {
      int r = t >> 2, kc = t & 3;
      *(uint4*)&Ab[r * 32 + kc * 8] = *(const uint4*)&A[(size_t)(m0 + r) * 512 + k0 + kc * 8];
    }
#pragma unroll
    for (int i = 0; i < 2; ++i) {
      int c = t + i * 256;
      int r = c >> 2, kc = c & 3;
      *(uint4*)&Bb[r * 32 + kc * 8] = *(const uint4*)&BT[(size_t)r * 512 + k0 + kc * 8];
    }
    __syncthreads();
    short8 aF[2], bF[4];
#pragma unroll
    for (int mi = 0; mi < 2; ++mi) aF[mi] = *(const short8*)&Ab[(wr + mi * 16 + (l & 15)) * 32 + (l >> 4) * 8];
#pragma unroll
    for (int nj = 0; nj < 4; ++nj) bF[nj] = *(const short8*)&Bb[(wc + nj * 16 + (l & 15)) * 32 + (l >> 4) * 8];
#pragma unroll
    for (int mi = 0; mi < 2; ++mi)
#pragma unroll
      for (int nj = 0; nj < 4; ++nj)
        acc[mi][nj] = __builtin_amdgcn_mfma_f32_16x16x32_bf16(aF[mi], bF[nj], acc[mi][nj], 0, 0, 0);
    __syncthreads();
  }
#pragma unroll
  for (int mi = 0; mi < 2; ++mi)
#pragma unroll
    for (int nj = 0; nj < 4; ++nj)
#pragma unroll
      for (int r = 0; r < 4; ++r) {
        int row = wr + mi * 16 + ((l >> 4) << 2) + r;
        int col = wc + nj * 16 + (l & 15);
        tld[row][col] = acc[mi][nj][r] + b2[col];
      }
  __syncthreads();
  {
    int row = t >> 2, part = t & 3;
    int src = cl[m0 + row];
    const float* rr = n1 + (size_t)(m0 + row) * CC + part * 32;
    const float* xr = x + (size_t)src * CC + part * 32;
    float dot = 0.f;
#pragma unroll
    for (int j = 0; j < 32; ++j) {
      int c = part * 32 + j;
      dot += tld[row][c] * w0g[c] + rr[j] * w1g[c];
    }
    dot += __shfl_xor(dot, 1); dot += __shfl_xor(dot, 2);
    float g = 1.0f / (1.0f + __expf(-dot));
#pragma unroll
    for (int j = 0; j < 32; ++j) {
      int c = part * 32 + j;
      out[(size_t)src * CC + c] = xr[j] + tld[row][c] * g + rr[j] * (1.0f - g);
    }
  }
}

extern "C" void kernel_launch(void* const* d_in, const int* in_sizes, int n_in,
                              void* d_out, int out_size, void* d_ws, size_t ws_size,
                              hipStream_t stream) {
  const float* x       = (const float*)d_in[0];
  const int*   edge    = (const int*)d_in[1];
  const int*   clusters= (const int*)d_in[2];
  const float* adj_emb = (const float*)d_in[3];
  const float* ln1_g   = (const float*)d_in[4];
  const float* ln1_b   = (const float*)d_in[5];
  const float* Wq      = (const float*)d_in[6];
  const float* bq      = (const float*)d_in[7];
  const float* Wkv     = (const float*)d_in[8];
  const float* bkv     = (const float*)d_in[9];
  const float* We      = (const float*)d_in[10];
  const float* be      = (const float*)d_in[11];
  const float* Wo      = (const float*)d_in[12];
  const float* bo      = (const float*)d_in[13];
  const float* gate1   = (const float*)d_in[14];
  const float* ln2_g   = (const float*)d_in[15];
  const float* ln2_b   = (const float*)d_in[16];
  const float* W1      = (const float*)d_in[17];
  const float* b1      = (const float*)d_in[18];
  const float* W2      = (const float*)d_in[19];
  const float* b2      = (const float*)d_in[20];
  const float* gate2   = (const float*)d_in[21];

  char* wsb = (char*)d_ws;
  unsigned* adjw  = (unsigned*)wsb;                 // 64 KB
  float* e01   = (float*)(wsb + 65536);             // 4 KB
  float* cosF  = (float*)(wsb + 69632);             // 32 KB
  float* sinF  = (float*)(wsb + 102400);            // 32 KB
  ushort* WqkvT= (ushort*)(wsb + 135168);           // 384 KB
  ushort* WoT  = (ushort*)(wsb + 528384);           // 128 KB
  ushort* W1T  = (ushort*)(wsb + 659456);           // 128 KB
  ushort* W2T  = (ushort*)(wsb + 790528);           // 128 KB
  ushort* y    = (ushort*)(wsb + 921600);           // 1 MB
  ushort* P    = (ushort*)(wsb + 1970176);          // 12 MB (4096x1536 bf16)
  ushort* AO   = (ushort*)(wsb + 14553088);         // 4 MB
  float* n1    = (float*)(wsb + 18747392);          // 2 MB
  ushort* ffh  = (ushort*)(wsb + 20844544);         // 4 MB
  ushort* y2   = y;  // reuse

  pre_kernel<<<1552, 256, 0, stream>>>(Wq, Wkv, Wo, W1, W2, adj_emb, We, be,
                                       WqkvT, WoT, W1T, W2T, e01, cosF, sinF, adjw);
  build_adj_kernel<<<EE / 256, 256, 0, stream>>>(edge, adjw);
  ln_kernel<<<NNODES / 4, 256, 0, stream>>>(x, clusters, ln1_g, ln1_b, y);
  qkv_gemm_kernel<<<dim3(12, 32), 256, 0, stream>>>(y, WqkvT, bq, bkv, cosF, sinF, P);
  attn_kernel<<<KCL * HH, 512, 0, stream>>>(P, adjw, e01, AO);
  wo_gate_kernel<<<64, 256, 0, stream>>>(AO, WoT, bo, x, clusters, gate1, ln2_g, ln2_b, n1, y2);
  w1_gemm_kernel<<<dim3(4, 32), 256, 0, stream>>>(y2, W1T, b1, ffh);
  w2_final_kernel<<<64, 256, 0, stream>>>(ffh, W2T, b2, n1, x, clusters, gate2, (float*)d_out);
}

// Round 4
// 77.440 us; speedup vs baseline: 2.2265x; 1.1823x over previous
//
#include <hip/hip_runtime.h>
#include <math.h>

#define NNODES 4096
#define CC     128
#define KCL    32
#define MM     128
#define EE     65536
#define HH     8
#define DD     64
#define INNERD 512

typedef __attribute__((ext_vector_type(8))) short short8;
typedef __attribute__((ext_vector_type(4))) float f32x4;

__device__ __forceinline__ float bf2f(ushort u) { return __uint_as_float(((unsigned)u) << 16); }
__device__ __forceinline__ ushort f2bf(float f) {
  unsigned b = __float_as_uint(f);
  return (ushort)((b + 0x7FFFu + ((b >> 16) & 1u)) >> 16);
}

// ================= pre: tiled W transposes + e01 + rotary tables + adj zero + LN1 ====
// blocks 0..383    : 32x32 tiled transposes of the 5 weight matrices (fp32 -> bf16 [n][k])
// blocks 384..387  : e01 (adj_emb @ We + be)
// blocks 388..395  : rotary cos/sin tables [i][d]
// blocks 396..399  : zero adjw
// blocks 400..1423 : LN1 of x[clusters] -> y bf16 (4 rows per block, wave per row)
__global__ __launch_bounds__(256) void pre_kernel(const float* __restrict__ Wq,
                                                  const float* __restrict__ Wkv,
                                                  const float* __restrict__ Wo,
                                                  const float* __restrict__ W1,
                                                  const float* __restrict__ W2,
                                                  const float* __restrict__ adj_emb,
                                                  const float* __restrict__ We,
                                                  const float* __restrict__ be,
                                                  const float* __restrict__ x,
                                                  const int* __restrict__ cl,
                                                  const float* __restrict__ ln1g,
                                                  const float* __restrict__ ln1b,
                                                  ushort* __restrict__ WqkvT,
                                                  ushort* __restrict__ WoT,
                                                  ushort* __restrict__ W1T,
                                                  ushort* __restrict__ W2T,
                                                  float* __restrict__ e01,
                                                  float* __restrict__ cosF,
                                                  float* __restrict__ sinF,
                                                  unsigned* __restrict__ adjw,
                                                  ushort* __restrict__ y) {
  __shared__ float lds[32][33];
  int bid = blockIdx.x, t = threadIdx.x;
  if (bid < 384) {
    // tile ranges: Wq 64 | Wkv 128 | Wo 64 | W1 64 | W2 64
    const float* src; ushort* dst; int N, K, tile;
    if (bid < 64)        { src = Wq;  dst = WqkvT;             N = 512;  K = 128; tile = bid; }
    else if (bid < 192)  { src = Wkv; dst = WqkvT + 512 * 128; N = 1024; K = 128; tile = bid - 64; }
    else if (bid < 256)  { src = Wo;  dst = WoT;               N = 128;  K = 512; tile = bid - 192; }
    else if (bid < 320)  { src = W1;  dst = W1T;               N = 512;  K = 128; tile = bid - 256; }
    else                 { src = W2;  dst = W2T;               N = 128;  K = 512; tile = bid - 320; }
    int tilesN = N >> 5;
    int k0 = (tile / tilesN) << 5, n0 = (tile % tilesN) << 5;
#pragma unroll
    for (int i = 0; i < 4; ++i) {
      int idx = i * 256 + t, kk = idx >> 5, nn = idx & 31;
      lds[kk][nn] = src[(size_t)(k0 + kk) * N + n0 + nn];
    }
    __syncthreads();
#pragma unroll
    for (int i = 0; i < 4; ++i) {
      int idx = i * 256 + t, nn = idx >> 5, kk = idx & 31;
      dst[(size_t)(n0 + nn) * K + k0 + kk] = f2bf(lds[nn & 0 ? 0 : kk][nn]);  // lds[kk][nn]
    }
  } else if (bid < 388) {
    int idx = (bid - 384) * 256 + t;  // 0..1023
    int which = idx >> 9, col = idx & 511;
    float a = 0.f;
    for (int c = 0; c < CC; ++c) a += adj_emb[which * CC + c] * We[(size_t)c * INNERD + col];
    e01[idx] = a + be[col];
  } else if (bid < 396) {
#pragma unroll
    for (int e = 0; e < 4; ++e) {
      int idx = ((bid - 388) * 256 + t) * 4 + e;  // 0..8191
      int i = idx >> 6, d = idx & 63, p = d >> 1;
      float inv = exp2f(-(float)p * (13.287712379549449f / 32.0f)); // 10000^(-p/32)
      float ang = (float)i * inv;
      cosF[idx] = cosf(ang);
      sinF[idx] = sinf(ang);
    }
  } else if (bid < 400) {
    int base = ((bid - 396) * 256 + t) * 16;
#pragma unroll
    for (int e = 0; e < 16; ++e) adjw[base + e] = 0u;
  } else {
    int row = (bid - 400) * 4 + (t >> 6);
    int lane = t & 63;
    int src = cl[row];
    const float* p = x + (size_t)src * CC;
    float2 v = *(const float2*)(p + lane * 2);
    float s = v.x + v.y, q = v.x * v.x + v.y * v.y;
#pragma unroll
    for (int o = 32; o; o >>= 1) { s += __shfl_xor(s, o); q += __shfl_xor(q, o); }
    float mu = s * (1.0f / CC);
    float var = q * (1.0f / CC) - mu * mu;
    float rs = rsqrtf(var + 1e-5f);
    float2 g2 = *(const float2*)(ln1g + lane * 2);
    float2 b2 = *(const float2*)(ln1b + lane * 2);
    float ox = (v.x - mu) * rs * g2.x + b2.x;
    float oy = (v.y - mu) * rs * g2.y + b2.y;
    *(unsigned*)&y[(size_t)row * CC + lane * 2] = (unsigned)f2bf(ox) | ((unsigned)f2bf(oy) << 16);
  }
}

// ========== QKV GEMM (fused rotary) + adjacency build (extra blocks) ==========
// blocks 0..383: GEMM P = [q|k|v] = y @ WqkvT^T + b, rotary on cols < 1024
// blocks 384..639: adjacency bitmask scatter
__global__ __launch_bounds__(256) void qkv_adj_kernel(const ushort* __restrict__ A,
                                                      const ushort* __restrict__ BT,
                                                      const float* __restrict__ bq,
                                                      const float* __restrict__ bkv,
                                                      const float* __restrict__ cosF,
                                                      const float* __restrict__ sinF,
                                                      const int* __restrict__ ei,
                                                      unsigned* __restrict__ adjw,
                                                      ushort* __restrict__ P) {
  __shared__ __align__(16) ushort Ab[128 * 32];
  __shared__ __align__(16) ushort Bb[128 * 32];
  int bid = blockIdx.x, t = threadIdx.x;
  if (bid >= 384) {
    int e = (bid - 384) * 256 + t;
    int s = ei[e], d = ei[EE + e];
    int cs = s >> 7, cd = d >> 7;
    if (cs == cd) {
      int flat = cs * (MM * MM) + (s & 127) * MM + (d & 127);
      atomicOr(adjw + (flat >> 5), 1u << (flat & 31));
    }
    return;
  }
  int w = t >> 6, l = t & 63;
  int nt = bid % 12, mt = bid / 12;
  int n0 = nt * 128, m0 = mt * 128;
  int wr = (w >> 1) * 64, wc = (w & 1) * 64;
  f32x4 acc[4][4];
#pragma unroll
  for (int mi = 0; mi < 4; ++mi)
#pragma unroll
    for (int nj = 0; nj < 4; ++nj) acc[mi][nj] = (f32x4){0.f, 0.f, 0.f, 0.f};

  for (int k0 = 0; k0 < 128; k0 += 32) {
#pragma unroll
    for (int i = 0; i < 2; ++i) {
      int c = t + i * 256;
      int r = c >> 2, kc = c & 3;
      *(uint4*)&Ab[r * 32 + kc * 8] = *(const uint4*)&A[(size_t)(m0 + r) * 128 + k0 + kc * 8];
      *(uint4*)&Bb[r * 32 + kc * 8] = *(const uint4*)&BT[(size_t)(n0 + r) * 128 + k0 + kc * 8];
    }
    __syncthreads();
    short8 aF[4], bF[4];
#pragma unroll
    for (int mi = 0; mi < 4; ++mi) aF[mi] = *(const short8*)&Ab[(wr + mi * 16 + (l & 15)) * 32 + (l >> 4) * 8];
#pragma unroll
    for (int nj = 0; nj < 4; ++nj) bF[nj] = *(const short8*)&Bb[(wc + nj * 16 + (l & 15)) * 32 + (l >> 4) * 8];
#pragma unroll
    for (int mi = 0; mi < 4; ++mi)
#pragma unroll
      for (int nj = 0; nj < 4; ++nj)
        acc[mi][nj] = __builtin_amdgcn_mfma_f32_16x16x32_bf16(aF[mi], bF[nj], acc[mi][nj], 0, 0, 0);
    __syncthreads();
  }
#pragma unroll
  for (int mi = 0; mi < 4; ++mi)
#pragma unroll
    for (int nj = 0; nj < 4; ++nj)
#pragma unroll
      for (int r = 0; r < 4; ++r) {
        int m = m0 + wr + mi * 16 + ((l >> 4) << 2) + r;
        int n = n0 + wc + nj * 16 + (l & 15);
        float bias = n < 512 ? bq[n] : bkv[n - 512];
        float v = acc[mi][nj][r] + bias;
        float partner = __shfl_xor(v, 1);
        if (n < 1024) {
          int d = n & 63, i = m & 127;
          float cv = cosF[i * 64 + d], sv = sinF[i * 64 + d];
          v = (n & 1) ? (v * cv + partner * sv) : (v * cv - partner * sv);
        }
        P[(size_t)m * 1536 + n] = f2bf(v);
      }
}

// ---------------- fused MFMA attention per (cluster, head), 512 threads ----------------
__global__ __launch_bounds__(512) void attn_kernel(const ushort* __restrict__ P,
                                                   const unsigned* __restrict__ adjw,
                                                   const float* __restrict__ e01,
                                                   ushort* __restrict__ AO) {
  __shared__ __align__(16) ushort QKP[2 * 128 * 64];  // Qb | Kb ; Pl overlays both
  __shared__ __align__(16) ushort VT[64 * 128];
  __shared__ unsigned adjL[512];
  __shared__ float e0s[64], e1s[64], qe0L[128], qe1L[128], sL[128];
  ushort* Qb = QKP;
  ushort* Kb = QKP + 8192;
  ushort* Pl = QKP;

  int t = threadIdx.x, w = t >> 6, l = t & 63;
  int kc = blockIdx.x >> 3, h = blockIdx.x & 7;

  const ushort* qg = P + (size_t)kc * 128 * 1536 + h * DD;

  for (int c = t; c < 1024; c += 512) {
    int r = c >> 3, ch = c & 7;
    uint4 qv = *(const uint4*)&qg[(size_t)r * 1536 + ch * 8];
    *(uint4*)&Qb[r * 64 + ((ch ^ (r & 7)) << 3)] = qv;
    uint4 kv = *(const uint4*)&qg[(size_t)r * 1536 + 512 + ch * 8];
    *(uint4*)&Kb[r * 64 + ((ch ^ (r & 7)) << 3)] = kv;
    uint4 vv = *(const uint4*)&qg[(size_t)r * 1536 + 1024 + ch * 8];
    const ushort* vp = (const ushort*)&vv;
#pragma unroll
    for (int e = 0; e < 8; ++e) {
      int d = ch * 8 + e;
      VT[d * 128 + (((r >> 3) ^ (d & 7)) << 3) + (r & 7)] = vp[e];
    }
  }
  adjL[t & 511] = adjw[kc * 512 + (t & 511)];
  if (t < 64) { e0s[t] = e01[h * DD + t]; e1s[t] = e01[512 + h * DD + t]; }
  __syncthreads();

  {
    int row = t >> 2, part = t & 3;
    float a0 = 0.f, a1 = 0.f;
#pragma unroll
    for (int dd = 0; dd < 16; ++dd) {
      int d = part * 16 + dd;
      float qv = bf2f(Qb[row * 64 + (((d >> 3) ^ (row & 7)) << 3) + (d & 7)]);
      a0 += qv * e0s[d]; a1 += qv * e1s[d];
    }
    a0 += __shfl_xor(a0, 1); a0 += __shfl_xor(a0, 2);
    a1 += __shfl_xor(a1, 1); a1 += __shfl_xor(a1, 2);
    if (part == 0) { qe0L[row] = a0; qe1L[row] = a1; }
  }
  __syncthreads();

  int m0 = w * 16;
  f32x4 s_acc[8];
#pragma unroll
  for (int nj = 0; nj < 8; ++nj) s_acc[nj] = (f32x4){0.f, 0.f, 0.f, 0.f};
  {
    int arow = m0 + (l & 15);
    short8 aF0 = *(const short8*)&Qb[arow * 64 + ((((l >> 4)) ^ (arow & 7)) << 3)];
    short8 aF1 = *(const short8*)&Qb[arow * 64 + (((4 + (l >> 4)) ^ (arow & 7)) << 3)];
#pragma unroll
    for (int nj = 0; nj < 8; ++nj) {
      int brow = nj * 16 + (l & 15);
      short8 b0 = *(const short8*)&Kb[brow * 64 + ((((l >> 4)) ^ (brow & 7)) << 3)];
      short8 b1 = *(const short8*)&Kb[brow * 64 + (((4 + (l >> 4)) ^ (brow & 7)) << 3)];
      s_acc[nj] = __builtin_amdgcn_mfma_f32_16x16x32_bf16(aF0, b0, s_acc[nj], 0, 0, 0);
      s_acc[nj] = __builtin_amdgcn_mfma_f32_16x16x32_bf16(aF1, b1, s_acc[nj], 0, 0, 0);
    }
  }

  float mrow[4], ssum[4], sadj[4];
#pragma unroll
  for (int r = 0; r < 4; ++r) {
    int i = m0 + ((l >> 4) << 2) + r;
    float q0 = qe0L[i], q1 = qe1L[i];
    unsigned w0 = adjL[i * 4 + 0], w1 = adjL[i * 4 + 1], w2 = adjL[i * 4 + 2], w3 = adjL[i * 4 + 3];
    float mx = -1e30f;
#pragma unroll
    for (int nj = 0; nj < 8; ++nj) {
      unsigned word = (nj >> 1) == 0 ? w0 : (nj >> 1) == 1 ? w1 : (nj >> 1) == 2 ? w2 : w3;
      unsigned bit = (word >> (((nj & 1) << 4) + (l & 15))) & 1u;
      float s = (s_acc[nj][r] + (bit ? q1 : q0)) * 0.125f;
      s_acc[nj][r] = s;
      mx = fmaxf(mx, s);
    }
    mrow[r] = mx;
  }
#pragma unroll
  for (int o = 1; o < 16; o <<= 1)
#pragma unroll
    for (int r = 0; r < 4; ++r) mrow[r] = fmaxf(mrow[r], __shfl_xor(mrow[r], o));
#pragma unroll
  for (int r = 0; r < 4; ++r) {
    float sum = 0.f;
#pragma unroll
    for (int nj = 0; nj < 8; ++nj) {
      float p = __expf(s_acc[nj][r] - mrow[r]);
      s_acc[nj][r] = p;
      sum += p;
    }
    ssum[r] = sum;
  }
#pragma unroll
  for (int o = 1; o < 16; o <<= 1)
#pragma unroll
    for (int r = 0; r < 4; ++r) ssum[r] += __shfl_xor(ssum[r], o);
#pragma unroll
  for (int r = 0; r < 4; ++r) {
    int i = m0 + ((l >> 4) << 2) + r;
    unsigned w0 = adjL[i * 4 + 0], w1 = adjL[i * 4 + 1], w2 = adjL[i * 4 + 2], w3 = adjL[i * 4 + 3];
    float inv = 1.0f / ssum[r];
    float sa = 0.f;
#pragma unroll
    for (int nj = 0; nj < 8; ++nj) {
      unsigned word = (nj >> 1) == 0 ? w0 : (nj >> 1) == 1 ? w1 : (nj >> 1) == 2 ? w2 : w3;
      unsigned bit = (word >> (((nj & 1) << 4) + (l & 15))) & 1u;
      float p = s_acc[nj][r] * inv;
      s_acc[nj][r] = p;
      if (bit) sa += p;
    }
    sadj[r] = sa;
  }
#pragma unroll
  for (int o = 1; o < 16; o <<= 1)
#pragma unroll
    for (int r = 0; r < 4; ++r) sadj[r] += __shfl_xor(sadj[r], o);

  __syncthreads();

#pragma unroll
  for (int r = 0; r < 4; ++r) {
    int i = m0 + ((l >> 4) << 2) + r;
#pragma unroll
    for (int nj = 0; nj < 8; ++nj) {
      int j = nj * 16 + (l & 15);
      Pl[i * 128 + (((j >> 3) ^ (i & 7)) << 3) + (j & 7)] = f2bf(s_acc[nj][r]);
    }
    if ((l & 15) == 0) sL[i] = sadj[r];
  }
  __syncthreads();

  f32x4 o_acc[4];
#pragma unroll
  for (int nj = 0; nj < 4; ++nj) o_acc[nj] = (f32x4){0.f, 0.f, 0.f, 0.f};
#pragma unroll
  for (int kk = 0; kk < 4; ++kk) {
    int prow = m0 + (l & 15);
    int ch = kk * 4 + (l >> 4);
    short8 pa = *(const short8*)&Pl[prow * 128 + ((ch ^ (prow & 7)) << 3)];
#pragma unroll
    for (int nj = 0; nj < 4; ++nj) {
      int vrow = nj * 16 + (l & 15);
      short8 vf = *(const short8*)&VT[vrow * 128 + ((ch ^ (vrow & 7)) << 3)];
      o_acc[nj] = __builtin_amdgcn_mfma_f32_16x16x32_bf16(pa, vf, o_acc[nj], 0, 0, 0);
    }
  }
#pragma unroll
  for (int nj = 0; nj < 4; ++nj)
#pragma unroll
    for (int r = 0; r < 4; ++r) {
      int i = m0 + ((l >> 4) << 2) + r;
      int d = nj * 16 + (l & 15);
      float s = sL[i];
      float v = o_acc[nj][r] + e0s[d] * (1.0f - s) + e1s[d] * s;
      AO[(size_t)(kc * 128 + i) * INNERD + h * DD + d] = f2bf(v);
    }
}

// ---------------- Wo GEMM + gate1 + LN2 : M-tile 32, N=128 full ----------------
__global__ __launch_bounds__(256) void wo_gate_kernel(const ushort* __restrict__ A,
                                                      const ushort* __restrict__ BT,
                                                      const float* __restrict__ bo,
                                                      const float* __restrict__ x,
                                                      const int* __restrict__ cl,
                                                      const float* __restrict__ g1,
                                                      const float* __restrict__ lng,
                                                      const float* __restrict__ lnb,
                                                      float* __restrict__ n1,
                                                      ushort* __restrict__ y2) {
  __shared__ __align__(16) ushort Ab[32 * 32];
  __shared__ __align__(16) ushort Bb[128 * 32];
  __shared__ float tld[32][132];
  __shared__ float w0g[128], w1g[128], lnGs[128], lnBs[128];
  int t = threadIdx.x, w = t >> 6, l = t & 63;
  int m0 = blockIdx.x * 32;
  int wr = (w >> 1) * 16, wc = (w & 1) * 64;
  if (t < 128) { w0g[t] = g1[t] + g1[256 + t]; w1g[t] = g1[128 + t] - g1[256 + t]; }
  else { lnGs[t - 128] = lng[t - 128]; lnBs[t - 128] = lnb[t - 128]; }
  f32x4 acc[4];
#pragma unroll
  for (int nj = 0; nj < 4; ++nj) acc[nj] = (f32x4){0.f, 0.f, 0.f, 0.f};
  for (int k0 = 0; k0 < 512; k0 += 32) {
    if (t < 128) {
      int r = t >> 2, kc = t & 3;
      *(uint4*)&Ab[r * 32 + kc * 8] = *(const uint4*)&A[(size_t)(m0 + r) * 512 + k0 + kc * 8];
    }
#pragma unroll
    for (int i = 0; i < 2; ++i) {
      int c = t + i * 256;
      int r = c >> 2, kc = c & 3;
      *(uint4*)&Bb[r * 32 + kc * 8] = *(const uint4*)&BT[(size_t)r * 512 + k0 + kc * 8];
    }
    __syncthreads();
    short8 aF = *(const short8*)&Ab[(wr + (l & 15)) * 32 + (l >> 4) * 8];
#pragma unroll
    for (int nj = 0; nj < 4; ++nj) {
      short8 bF = *(const short8*)&Bb[(wc + nj * 16 + (l & 15)) * 32 + (l >> 4) * 8];
      acc[nj] = __builtin_amdgcn_mfma_f32_16x16x32_bf16(aF, bF, acc[nj], 0, 0, 0);
    }
    __syncthreads();
  }
#pragma unroll
  for (int nj = 0; nj < 4; ++nj)
#pragma unroll
    for (int r = 0; r < 4; ++r) {
      int row = wr + ((l >> 4) << 2) + r;
      int col = wc + nj * 16 + (l & 15);
      tld[row][col] = acc[nj][r] + bo[col];
    }
  __syncthreads();
  {
    int row = t >> 3, part = t & 7;
    int src = cl[m0 + row];
    const float* xr = x + (size_t)src * CC + part * 16;
    float dot = 0.f;
#pragma unroll
    for (int j = 0; j < 16; ++j) {
      int c = part * 16 + j;
      dot += tld[row][c] * w0g[c] + xr[j] * w1g[c];
    }
    dot += __shfl_xor(dot, 1); dot += __shfl_xor(dot, 2); dot += __shfl_xor(dot, 4);
    float g = 1.0f / (1.0f + __expf(-dot));
    float s = 0.f, q = 0.f;
#pragma unroll
    for (int j = 0; j < 16; ++j) {
      int c = part * 16 + j;
      float nv = tld[row][c] * g + xr[j] * (1.0f - g);
      tld[row][c] = nv;
      n1[(size_t)(m0 + row) * CC + c] = nv;
      s += nv; q += nv * nv;
    }
    s += __shfl_xor(s, 1); s += __shfl_xor(s, 2); s += __shfl_xor(s, 4);
    q += __shfl_xor(q, 1); q += __shfl_xor(q, 2); q += __shfl_xor(q, 4);
    float mu = s * (1.0f / CC);
    float var = q * (1.0f / CC) - mu * mu;
    float rs = rsqrtf(var + 1e-5f);
#pragma unroll
    for (int j = 0; j < 16; ++j) {
      int c = part * 16 + j;
      y2[(size_t)(m0 + row) * CC + c] = f2bf((tld[row][c] - mu) * rs * lnGs[c] + lnBs[c]);
    }
  }
}

// ---------------- W1 GEMM + exact GELU -> ffh bf16 (64x128 tile) ----------------
__global__ __launch_bounds__(256) void w1_gemm_kernel(const ushort* __restrict__ A,
                                                      const ushort* __restrict__ BT,
                                                      const float* __restrict__ bias,
                                                      ushort* __restrict__ Cout) {
  __shared__ __align__(16) ushort Ab[64 * 32];
  __shared__ __align__(16) ushort Bb[128 * 32];
  int t = threadIdx.x;
  int w = t >> 6, l = t & 63;
  int n0 = blockIdx.x * 128, m0 = blockIdx.y * 64;
  int wr = (w >> 1) * 32, wc = (w & 1) * 64;
  f32x4 acc[2][4];
#pragma unroll
  for (int mi = 0; mi < 2; ++mi)
#pragma unroll
    for (int nj = 0; nj < 4; ++nj) acc[mi][nj] = (f32x4){0.f, 0.f, 0.f, 0.f};
  for (int k0 = 0; k0 < 128; k0 += 32) {
    {
      int r = t >> 2, kc = t & 3;
      *(uint4*)&Ab[r * 32 + kc * 8] = *(const uint4*)&A[(size_t)(m0 + r) * 128 + k0 + kc * 8];
    }
#pragma unroll
    for (int i = 0; i < 2; ++i) {
      int c = t + i * 256;
      int r = c >> 2, kc = c & 3;
      *(uint4*)&Bb[r * 32 + kc * 8] = *(const uint4*)&BT[(size_t)(n0 + r) * 128 + k0 + kc * 8];
    }
    __syncthreads();
    short8 aF[2], bF[4];
#pragma unroll
    for (int mi = 0; mi < 2; ++mi) aF[mi] = *(const short8*)&Ab[(wr + mi * 16 + (l & 15)) * 32 + (l >> 4) * 8];
#pragma unroll
    for (int nj = 0; nj < 4; ++nj) bF[nj] = *(const short8*)&Bb[(wc + nj * 16 + (l & 15)) * 32 + (l >> 4) * 8];
#pragma unroll
    for (int mi = 0; mi < 2; ++mi)
#pragma unroll
      for (int nj = 0; nj < 4; ++nj)
        acc[mi][nj] = __builtin_amdgcn_mfma_f32_16x16x32_bf16(aF[mi], bF[nj], acc[mi][nj], 0, 0, 0);
    __syncthreads();
  }
#pragma unroll
  for (int mi = 0; mi < 2; ++mi)
#pragma unroll
    for (int nj = 0; nj < 4; ++nj)
#pragma unroll
      for (int r = 0; r < 4; ++r) {
        int m = m0 + wr + mi * 16 + ((l >> 4) << 2) + r;
        int n = n0 + wc + nj * 16 + (l & 15);
        float v = acc[mi][nj][r] + bias[n];
        v = 0.5f * v * (1.0f + erff(v * 0.70710678118654752f));
        Cout[(size_t)m * 512 + n] = f2bf(v);
      }
}

// ---------------- W2 GEMM + gate2 + final add : M-tile 32 ----------------
__global__ __launch_bounds__(256) void w2_final_kernel(const ushort* __restrict__ A,
                                                       const ushort* __restrict__ BT,
                                                       const float* __restrict__ b2,
                                                       const float* __restrict__ n1,
                                                       const float* __restrict__ x,
                                                       const int* __restrict__ cl,
                                                       const float* __restrict__ g2,
                                                       float* __restrict__ out) {
  __shared__ __align__(16) ushort Ab[32 * 32];
  __shared__ __align__(16) ushort Bb[128 * 32];
  __shared__ float tld[32][132];
  __shared__ float w0g[128], w1g[128];
  int t = threadIdx.x, w = t >> 6, l = t & 63;
  int m0 = blockIdx.x * 32;
  int wr = (w >> 1) * 16, wc = (w & 1) * 64;
  if (t < 128) { w0g[t] = g2[t] + g2[256 + t]; w1g[t] = g2[128 + t] - g2[256 + t]; }
  f32x4 acc[4];
#pragma unroll
  for (int nj = 0; nj < 4; ++nj) acc[nj] = (f32x4){0.f, 0.f, 0.f, 0.f};
  for (int k0 = 0; k0 < 512; k0 += 32) {
    if (t < 128) {
      int r = t >> 2, kc = t & 3;
      *(uint4*)&Ab[r * 32 + kc * 8] = *(const uint4*)&A[(size_t)(m0 + r) * 512 + k0 + kc * 8];
    }
#pragma unroll
    for (int i = 0; i < 2; ++i) {
      int c = t + i * 256;
      int r = c >> 2, kc = c & 3;
      *(uint4*)&Bb[r * 32 + kc * 8] = *(const uint4*)&BT[(size_t)r * 512 + k0 + kc * 8];
    }
    __syncthreads();
    short8 aF = *(const short8*)&Ab[(wr + (l & 15)) * 32 + (l >> 4) * 8];
#pragma unroll
    for (int nj = 0; nj < 4; ++nj) {
      short8 bF = *(const short8*)&Bb[(wc + nj * 16 + (l & 15)) * 32 + (l >> 4) * 8];
      acc[nj] = __builtin_amdgcn_mfma_f32_16x16x32_bf16(aF, bF, acc[nj], 0, 0, 0);
    }
    __syncthreads();
  }
#pragma unroll
  for (int nj = 0; nj < 4; ++nj)
#pragma unroll
    for (int r = 0; r < 4; ++r) {
      int row = wr + ((l >> 4) << 2) + r;
      int col = wc + nj * 16 + (l & 15);
      tld[row][col] = acc[nj][r] + b2[col];
    }
  __syncthreads();
  {
    int row = t >> 3, part = t & 7;
    int src = cl[m0 + row];
    const float* rr = n1 + (size_t)(m0 + row) * CC + part * 16;
    const float* xr = x + (size_t)src * CC + part * 16;
    float dot = 0.f;
#pragma unroll
    for (int j = 0; j < 16; ++j) {
      int c = part * 16 + j;
      dot += tld[row][c] * w0g[c] + rr[j] * w1g[c];
    }
    dot += __shfl_xor(dot, 1); dot += __shfl_xor(dot, 2); dot += __shfl_xor(dot, 4);
    float g = 1.0f / (1.0f + __expf(-dot));
#pragma unroll
    for (int j = 0; j < 16; ++j) {
      int c = part * 16 + j;
      out[(size_t)src * CC + c] = xr[j] + tld[row][c] * g + rr[j] * (1.0f - g);
    }
  }
}

extern "C" void kernel_launch(void* const* d_in, const int* in_sizes, int n_in,
                              void* d_out, int out_size, void* d_ws, size_t ws_size,
                              hipStream_t stream) {
  const float* x       = (const float*)d_in[0];
  const int*   edge    = (const int*)d_in[1];
  const int*   clusters= (const int*)d_in[2];
  const float* adj_emb = (const float*)d_in[3];
  const float* ln1_g   = (const float*)d_in[4];
  const float* ln1_b   = (const float*)d_in[5];
  const float* Wq      = (const float*)d_in[6];
  const float* bq      = (const float*)d_in[7];
  const float* Wkv     = (const float*)d_in[8];
  const float* bkv     = (const float*)d_in[9];
  const float* We      = (const float*)d_in[10];
  const float* be      = (const float*)d_in[11];
  const float* Wo      = (const float*)d_in[12];
  const float* bo      = (const float*)d_in[13];
  const float* gate1   = (const float*)d_in[14];
  const float* ln2_g   = (const float*)d_in[15];
  const float* ln2_b   = (const float*)d_in[16];
  const float* W1      = (const float*)d_in[17];
  const float* b1      = (const float*)d_in[18];
  const float* W2      = (const float*)d_in[19];
  const float* b2      = (const float*)d_in[20];
  const float* gate2   = (const float*)d_in[21];

  char* wsb = (char*)d_ws;
  unsigned* adjw  = (unsigned*)wsb;                 // 64 KB
  float* e01   = (float*)(wsb + 65536);             // 4 KB
  float* cosF  = (float*)(wsb + 69632);             // 32 KB
  float* sinF  = (float*)(wsb + 102400);            // 32 KB
  ushort* WqkvT= (ushort*)(wsb + 135168);           // 384 KB
  ushort* WoT  = (ushort*)(wsb + 528384);           // 128 KB
  ushort* W1T  = (ushort*)(wsb + 659456);           // 128 KB
  ushort* W2T  = (ushort*)(wsb + 790528);           // 128 KB
  ushort* y    = (ushort*)(wsb + 921600);           // 1 MB
  ushort* P    = (ushort*)(wsb + 1970176);          // 12 MB (4096x1536 bf16)
  ushort* AO   = (ushort*)(wsb + 14553088);         // 4 MB
  float* n1    = (float*)(wsb + 18747392);          // 2 MB
  ushort* ffh  = (ushort*)(wsb + 20844544);         // 4 MB
  ushort* y2   = y;  // reuse

  pre_kernel<<<1424, 256, 0, stream>>>(Wq, Wkv, Wo, W1, W2, adj_emb, We, be,
                                       x, clusters, ln1_g, ln1_b,
                                       WqkvT, WoT, W1T, W2T, e01, cosF, sinF, adjw, y);
  qkv_adj_kernel<<<640, 256, 0, stream>>>(y, WqkvT, bq, bkv, cosF, sinF, edge, adjw, P);
  attn_kernel<<<KCL * HH, 512, 0, stream>>>(P, adjw, e01, AO);
  wo_gate_kernel<<<128, 256, 0, stream>>>(AO, WoT, bo, x, clusters, gate1, ln2_g, ln2_b, n1, y2);
  w1_gemm_kernel<<<dim3(4, 64), 256, 0, stream>>>(y2, W1T, b1, ffh);
  w2_final_kernel<<<128, 256, 0, stream>>>(ffh, W2T, b2, n1, x, clusters, gate2, (float*)d_out);
}

// Round 5
// 77.169 us; speedup vs baseline: 2.2343x; 1.0035x over previous
//
#include <hip/hip_runtime.h>
#include <math.h>

#define NNODES 4096
#define CC     128
#define KCL    32
#define MM     128
#define EE     65536
#define HH     8
#define DD     64
#define INNERD 512

typedef __attribute__((ext_vector_type(8))) short short8;
typedef __attribute__((ext_vector_type(4))) float f32x4;

__device__ __forceinline__ float bf2f(ushort u) { return __uint_as_float(((unsigned)u) << 16); }
__device__ __forceinline__ ushort f2bf(float f) {
  unsigned b = __float_as_uint(f);
  return (ushort)((b + 0x7FFFu + ((b >> 16) & 1u)) >> 16);
}

// ================= pre: tiled W transposes + e01 + rotary tables + adj zero + LN1 ====
__global__ __launch_bounds__(256) void pre_kernel(const float* __restrict__ Wq,
                                                  const float* __restrict__ Wkv,
                                                  const float* __restrict__ Wo,
                                                  const float* __restrict__ W1,
                                                  const float* __restrict__ W2,
                                                  const float* __restrict__ adj_emb,
                                                  const float* __restrict__ We,
                                                  const float* __restrict__ be,
                                                  const float* __restrict__ x,
                                                  const int* __restrict__ cl,
                                                  const float* __restrict__ ln1g,
                                                  const float* __restrict__ ln1b,
                                                  ushort* __restrict__ WqkvT,
                                                  ushort* __restrict__ WoT,
                                                  ushort* __restrict__ W1T,
                                                  ushort* __restrict__ W2T,
                                                  float* __restrict__ e01,
                                                  float* __restrict__ cosF,
                                                  float* __restrict__ sinF,
                                                  unsigned* __restrict__ adjw,
                                                  ushort* __restrict__ y) {
  __shared__ float lds[32][33];
  int bid = blockIdx.x, t = threadIdx.x;
  if (bid < 384) {
    const float* src; ushort* dst; int N, K, tile;
    if (bid < 64)        { src = Wq;  dst = WqkvT;             N = 512;  K = 128; tile = bid; }
    else if (bid < 192)  { src = Wkv; dst = WqkvT + 512 * 128; N = 1024; K = 128; tile = bid - 64; }
    else if (bid < 256)  { src = Wo;  dst = WoT;               N = 128;  K = 512; tile = bid - 192; }
    else if (bid < 320)  { src = W1;  dst = W1T;               N = 512;  K = 128; tile = bid - 256; }
    else                 { src = W2;  dst = W2T;               N = 128;  K = 512; tile = bid - 320; }
    int tilesN = N >> 5;
    int k0 = (tile / tilesN) << 5, n0 = (tile % tilesN) << 5;
#pragma unroll
    for (int i = 0; i < 4; ++i) {
      int idx = i * 256 + t, kk = idx >> 5, nn = idx & 31;
      lds[kk][nn] = src[(size_t)(k0 + kk) * N + n0 + nn];
    }
    __syncthreads();
#pragma unroll
    for (int i = 0; i < 4; ++i) {
      int idx = i * 256 + t, nn = idx >> 5, kk = idx & 31;
      dst[(size_t)(n0 + nn) * K + k0 + kk] = f2bf(lds[kk][nn]);
    }
  } else if (bid < 388) {
    int idx = (bid - 384) * 256 + t;  // 0..1023
    int which = idx >> 9, col = idx & 511;
    float a = 0.f;
    for (int c = 0; c < CC; ++c) a += adj_emb[which * CC + c] * We[(size_t)c * INNERD + col];
    e01[idx] = a + be[col];
  } else if (bid < 396) {
#pragma unroll
    for (int e = 0; e < 4; ++e) {
      int idx = ((bid - 388) * 256 + t) * 4 + e;  // 0..8191
      int i = idx >> 6, d = idx & 63, p = d >> 1;
      float inv = exp2f(-(float)p * (13.287712379549449f / 32.0f)); // 10000^(-p/32)
      float ang = (float)i * inv;
      cosF[idx] = cosf(ang);
      sinF[idx] = sinf(ang);
    }
  } else if (bid < 400) {
    int base = ((bid - 396) * 256 + t) * 16;
#pragma unroll
    for (int e = 0; e < 16; ++e) adjw[base + e] = 0u;
  } else {
    int row = (bid - 400) * 4 + (t >> 6);
    int lane = t & 63;
    int src = cl[row];
    const float* p = x + (size_t)src * CC;
    float2 v = *(const float2*)(p + lane * 2);
    float s = v.x + v.y, q = v.x * v.x + v.y * v.y;
#pragma unroll
    for (int o = 32; o; o >>= 1) { s += __shfl_xor(s, o); q += __shfl_xor(q, o); }
    float mu = s * (1.0f / CC);
    float var = q * (1.0f / CC) - mu * mu;
    float rs = rsqrtf(var + 1e-5f);
    float2 g2 = *(const float2*)(ln1g + lane * 2);
    float2 b2 = *(const float2*)(ln1b + lane * 2);
    float ox = (v.x - mu) * rs * g2.x + b2.x;
    float oy = (v.y - mu) * rs * g2.y + b2.y;
    *(unsigned*)&y[(size_t)row * CC + lane * 2] = (unsigned)f2bf(ox) | ((unsigned)f2bf(oy) << 16);
  }
}

// ========== QKV GEMM (fused rotary) + adjacency build (extra blocks) ==========
__global__ __launch_bounds__(256) void qkv_adj_kernel(const ushort* __restrict__ A,
                                                      const ushort* __restrict__ BT,
                                                      const float* __restrict__ bq,
                                                      const float* __restrict__ bkv,
                                                      const float* __restrict__ cosF,
                                                      const float* __restrict__ sinF,
                                                      const int* __restrict__ ei,
                                                      unsigned* __restrict__ adjw,
                                                      ushort* __restrict__ P) {
  __shared__ __align__(16) ushort Ab[128 * 32];
  __shared__ __align__(16) ushort Bb[128 * 32];
  int bid = blockIdx.x, t = threadIdx.x;
  if (bid >= 384) {
    int e = (bid - 384) * 256 + t;
    int s = ei[e], d = ei[EE + e];
    int cs = s >> 7, cd = d >> 7;
    if (cs == cd) {
      int flat = cs * (MM * MM) + (s & 127) * MM + (d & 127);
      atomicOr(adjw + (flat >> 5), 1u << (flat & 31));
    }
    return;
  }
  int w = t >> 6, l = t & 63;
  int nt = bid % 12, mt = bid / 12;
  int n0 = nt * 128, m0 = mt * 128;
  int wr = (w >> 1) * 64, wc = (w & 1) * 64;
  f32x4 acc[4][4];
#pragma unroll
  for (int mi = 0; mi < 4; ++mi)
#pragma unroll
    for (int nj = 0; nj < 4; ++nj) acc[mi][nj] = (f32x4){0.f, 0.f, 0.f, 0.f};

  for (int k0 = 0; k0 < 128; k0 += 32) {
#pragma unroll
    for (int i = 0; i < 2; ++i) {
      int c = t + i * 256;
      int r = c >> 2, kc = c & 3;
      *(uint4*)&Ab[r * 32 + kc * 8] = *(const uint4*)&A[(size_t)(m0 + r) * 128 + k0 + kc * 8];
      *(uint4*)&Bb[r * 32 + kc * 8] = *(const uint4*)&BT[(size_t)(n0 + r) * 128 + k0 + kc * 8];
    }
    __syncthreads();
    short8 aF[4], bF[4];
#pragma unroll
    for (int mi = 0; mi < 4; ++mi) aF[mi] = *(const short8*)&Ab[(wr + mi * 16 + (l & 15)) * 32 + (l >> 4) * 8];
#pragma unroll
    for (int nj = 0; nj < 4; ++nj) bF[nj] = *(const short8*)&Bb[(wc + nj * 16 + (l & 15)) * 32 + (l >> 4) * 8];
#pragma unroll
    for (int mi = 0; mi < 4; ++mi)
#pragma unroll
      for (int nj = 0; nj < 4; ++nj)
        acc[mi][nj] = __builtin_amdgcn_mfma_f32_16x16x32_bf16(aF[mi], bF[nj], acc[mi][nj], 0, 0, 0);
    __syncthreads();
  }
#pragma unroll
  for (int mi = 0; mi < 4; ++mi)
#pragma unroll
    for (int nj = 0; nj < 4; ++nj)
#pragma unroll
      for (int r = 0; r < 4; ++r) {
        int m = m0 + wr + mi * 16 + ((l >> 4) << 2) + r;
        int n = n0 + wc + nj * 16 + (l & 15);
        float bias = n < 512 ? bq[n] : bkv[n - 512];
        float v = acc[mi][nj][r] + bias;
        float partner = __shfl_xor(v, 1);
        if (n < 1024) {
          int d = n & 63, i = m & 127;
          float cv = cosF[i * 64 + d], sv = sinF[i * 64 + d];
          v = (n & 1) ? (v * cv + partner * sv) : (v * cv - partner * sv);
        }
        P[(size_t)m * 1536 + n] = f2bf(v);
      }
}

// ---------------- fused MFMA attention per (cluster, head), 512 threads ----------------
__global__ __launch_bounds__(512) void attn_kernel(const ushort* __restrict__ P,
                                                   const unsigned* __restrict__ adjw,
                                                   const float* __restrict__ e01,
                                                   ushort* __restrict__ AO) {
  __shared__ __align__(16) ushort QKP[2 * 128 * 64];  // Qb | Kb ; Pl overlays both
  __shared__ __align__(16) ushort VT[64 * 128];
  __shared__ unsigned adjL[512];
  __shared__ float e0s[64], e1s[64], qe0L[128], qe1L[128], sL[128];
  ushort* Qb = QKP;
  ushort* Kb = QKP + 8192;
  ushort* Pl = QKP;

  int t = threadIdx.x, w = t >> 6, l = t & 63;
  int kc = blockIdx.x >> 3, h = blockIdx.x & 7;

  const ushort* qg = P + (size_t)kc * 128 * 1536 + h * DD;

  for (int c = t; c < 1024; c += 512) {
    int r = c >> 3, ch = c & 7;
    uint4 qv = *(const uint4*)&qg[(size_t)r * 1536 + ch * 8];
    *(uint4*)&Qb[r * 64 + ((ch ^ (r & 7)) << 3)] = qv;
    uint4 kv = *(const uint4*)&qg[(size_t)r * 1536 + 512 + ch * 8];
    *(uint4*)&Kb[r * 64 + ((ch ^ (r & 7)) << 3)] = kv;
    uint4 vv = *(const uint4*)&qg[(size_t)r * 1536 + 1024 + ch * 8];
    const ushort* vp = (const ushort*)&vv;
#pragma unroll
    for (int e = 0; e < 8; ++e) {
      int d = ch * 8 + e;
      VT[d * 128 + (((r >> 3) ^ (d & 7)) << 3) + (r & 7)] = vp[e];
    }
  }
  adjL[t & 511] = adjw[kc * 512 + (t & 511)];
  if (t < 64) { e0s[t] = e01[h * DD + t]; e1s[t] = e01[512 + h * DD + t]; }
  __syncthreads();

  {
    int row = t >> 2, part = t & 3;
    float a0 = 0.f, a1 = 0.f;
#pragma unroll
    for (int dd = 0; dd < 16; ++dd) {
      int d = part * 16 + dd;
      float qv = bf2f(Qb[row * 64 + (((d >> 3) ^ (row & 7)) << 3) + (d & 7)]);
      a0 += qv * e0s[d]; a1 += qv * e1s[d];
    }
    a0 += __shfl_xor(a0, 1); a0 += __shfl_xor(a0, 2);
    a1 += __shfl_xor(a1, 1); a1 += __shfl_xor(a1, 2);
    if (part == 0) { qe0L[row] = a0; qe1L[row] = a1; }
  }
  __syncthreads();

  int m0 = w * 16;
  f32x4 s_acc[8];
#pragma unroll
  for (int nj = 0; nj < 8; ++nj) s_acc[nj] = (f32x4){0.f, 0.f, 0.f, 0.f};
  {
    int arow = m0 + (l & 15);
    short8 aF0 = *(const short8*)&Qb[arow * 64 + ((((l >> 4)) ^ (arow & 7)) << 3)];
    short8 aF1 = *(const short8*)&Qb[arow * 64 + (((4 + (l >> 4)) ^ (arow & 7)) << 3)];
#pragma unroll
    for (int nj = 0; nj < 8; ++nj) {
      int brow = nj * 16 + (l & 15);
      short8 b0 = *(const short8*)&Kb[brow * 64 + ((((l >> 4)) ^ (brow & 7)) << 3)];
      short8 b1 = *(const short8*)&Kb[brow * 64 + (((4 + (l >> 4)) ^ (brow & 7)) << 3)];
      s_acc[nj] = __builtin_amdgcn_mfma_f32_16x16x32_bf16(aF0, b0, s_acc[nj], 0, 0, 0);
      s_acc[nj] = __builtin_amdgcn_mfma_f32_16x16x32_bf16(aF1, b1, s_acc[nj], 0, 0, 0);
    }
  }

  float mrow[4], ssum[4], sadj[4];
#pragma unroll
  for (int r = 0; r < 4; ++r) {
    int i = m0 + ((l >> 4) << 2) + r;
    float q0 = qe0L[i], q1 = qe1L[i];
    unsigned w0 = adjL[i * 4 + 0], w1 = adjL[i * 4 + 1], w2 = adjL[i * 4 + 2], w3 = adjL[i * 4 + 3];
    float mx = -1e30f;
#pragma unroll
    for (int nj = 0; nj < 8; ++nj) {
      unsigned word = (nj >> 1) == 0 ? w0 : (nj >> 1) == 1 ? w1 : (nj >> 1) == 2 ? w2 : w3;
      unsigned bit = (word >> (((nj & 1) << 4) + (l & 15))) & 1u;
      float s = (s_acc[nj][r] + (bit ? q1 : q0)) * 0.125f;
      s_acc[nj][r] = s;
      mx = fmaxf(mx, s);
    }
    mrow[r] = mx;
  }
#pragma unroll
  for (int o = 1; o < 16; o <<= 1)
#pragma unroll
    for (int r = 0; r < 4; ++r) mrow[r] = fmaxf(mrow[r], __shfl_xor(mrow[r], o));
#pragma unroll
  for (int r = 0; r < 4; ++r) {
    float sum = 0.f;
#pragma unroll
    for (int nj = 0; nj < 8; ++nj) {
      float p = __expf(s_acc[nj][r] - mrow[r]);
      s_acc[nj][r] = p;
      sum += p;
    }
    ssum[r] = sum;
  }
#pragma unroll
  for (int o = 1; o < 16; o <<= 1)
#pragma unroll
    for (int r = 0; r < 4; ++r) ssum[r] += __shfl_xor(ssum[r], o);
#pragma unroll
  for (int r = 0; r < 4; ++r) {
    int i = m0 + ((l >> 4) << 2) + r;
    unsigned w0 = adjL[i * 4 + 0], w1 = adjL[i * 4 + 1], w2 = adjL[i * 4 + 2], w3 = adjL[i * 4 + 3];
    float inv = 1.0f / ssum[r];
    float sa = 0.f;
#pragma unroll
    for (int nj = 0; nj < 8; ++nj) {
      unsigned word = (nj >> 1) == 0 ? w0 : (nj >> 1) == 1 ? w1 : (nj >> 1) == 2 ? w2 : w3;
      unsigned bit = (word >> (((nj & 1) << 4) + (l & 15))) & 1u;
      float p = s_acc[nj][r] * inv;
      s_acc[nj][r] = p;
      if (bit) sa += p;
    }
    sadj[r] = sa;
  }
#pragma unroll
  for (int o = 1; o < 16; o <<= 1)
#pragma unroll
    for (int r = 0; r < 4; ++r) sadj[r] += __shfl_xor(sadj[r], o);

  __syncthreads();

#pragma unroll
  for (int r = 0; r < 4; ++r) {
    int i = m0 + ((l >> 4) << 2) + r;
#pragma unroll
    for (int nj = 0; nj < 8; ++nj) {
      int j = nj * 16 + (l & 15);
      Pl[i * 128 + (((j >> 3) ^ (i & 7)) << 3) + (j & 7)] = f2bf(s_acc[nj][r]);
    }
    if ((l & 15) == 0) sL[i] = sadj[r];
  }
  __syncthreads();

  f32x4 o_acc[4];
#pragma unroll
  for (int nj = 0; nj < 4; ++nj) o_acc[nj] = (f32x4){0.f, 0.f, 0.f, 0.f};
#pragma unroll
  for (int kk = 0; kk < 4; ++kk) {
    int prow = m0 + (l & 15);
    int ch = kk * 4 + (l >> 4);
    short8 pa = *(const short8*)&Pl[prow * 128 + ((ch ^ (prow & 7)) << 3)];
#pragma unroll
    for (int nj = 0; nj < 4; ++nj) {
      int vrow = nj * 16 + (l & 15);
      short8 vf = *(const short8*)&VT[vrow * 128 + ((ch ^ (vrow & 7)) << 3)];
      o_acc[nj] = __builtin_amdgcn_mfma_f32_16x16x32_bf16(pa, vf, o_acc[nj], 0, 0, 0);
    }
  }
#pragma unroll
  for (int nj = 0; nj < 4; ++nj)
#pragma unroll
    for (int r = 0; r < 4; ++r) {
      int i = m0 + ((l >> 4) << 2) + r;
      int d = nj * 16 + (l & 15);
      float s = sL[i];
      float v = o_acc[nj][r] + e0s[d] * (1.0f - s) + e1s[d] * s;
      AO[(size_t)(kc * 128 + i) * INNERD + h * DD + d] = f2bf(v);
    }
}

// ===== fused tail: Wo GEMM + gate1 + LN2 + W1 GELU + W2 + gate2 + final add =====
// one block per 32 rows; n1 kept in registers; ffh overlays the AO LDS tile.
__global__ __launch_bounds__(256) void tail_kernel(const ushort* __restrict__ AO,
                                                   const ushort* __restrict__ WoT,
                                                   const float* __restrict__ bo,
                                                   const ushort* __restrict__ W1T,
                                                   const float* __restrict__ b1,
                                                   const ushort* __restrict__ W2T,
                                                   const float* __restrict__ b2,
                                                   const float* __restrict__ x,
                                                   const int* __restrict__ cl,
                                                   const float* __restrict__ g1,
                                                   const float* __restrict__ g2,
                                                   const float* __restrict__ lng,
                                                   const float* __restrict__ lnb,
                                                   float* __restrict__ out) {
  __shared__ __align__(16) ushort As[32 * 512];   // AO tile; ffh overlays after Wo
  __shared__ __align__(16) ushort Bb[128 * 32];
  __shared__ float tld[32][132];
  __shared__ __align__(16) ushort y2L[32 * 128];
  __shared__ float w0g1[128], w1g1[128], w0g2[128], w1g2[128], lnGs[128], lnBs[128];

  int t = threadIdx.x, w = t >> 6, l = t & 63;
  int m0 = blockIdx.x * 32;
  int wr = (w >> 1) * 16, wc = (w & 1) * 64;

  if (t < 128) {
    w0g1[t] = g1[t] + g1[256 + t]; w1g1[t] = g1[128 + t] - g1[256 + t];
    w0g2[t] = g2[t] + g2[256 + t]; w1g2[t] = g2[128 + t] - g2[256 + t];
  } else {
    lnGs[t - 128] = lng[t - 128]; lnBs[t - 128] = lnb[t - 128];
  }
  // stage AO tile (chunk-swizzled within aligned-8 groups)
  for (int c = t; c < 2048; c += 256) {
    int r = c >> 6, ch = c & 63;
    *(uint4*)&As[r * 512 + (((ch & ~7) | ((ch ^ r) & 7)) << 3)] =
        *(const uint4*)&AO[(size_t)(m0 + r) * 512 + ch * 8];
  }
  __syncthreads();

  // ---- Wo GEMM: [32x512] @ WoT[128][512]^T -> tld[32][128] ----
  f32x4 acc[4];
#pragma unroll
  for (int nj = 0; nj < 4; ++nj) acc[nj] = (f32x4){0.f, 0.f, 0.f, 0.f};
  for (int k0 = 0; k0 < 512; k0 += 32) {
#pragma unroll
    for (int i = 0; i < 2; ++i) {
      int c = t + i * 256;
      int r = c >> 2, kc = c & 3;
      *(uint4*)&Bb[r * 32 + kc * 8] = *(const uint4*)&WoT[(size_t)r * 512 + k0 + kc * 8];
    }
    __syncthreads();
    {
      int arow = wr + (l & 15);
      int gch = (k0 >> 3) + (l >> 4);
      short8 aF = *(const short8*)&As[arow * 512 + (((gch & ~7) | ((gch ^ arow) & 7)) << 3)];
#pragma unroll
      for (int nj = 0; nj < 4; ++nj) {
        short8 bF = *(const short8*)&Bb[(wc + nj * 16 + (l & 15)) * 32 + (l >> 4) * 8];
        acc[nj] = __builtin_amdgcn_mfma_f32_16x16x32_bf16(aF, bF, acc[nj], 0, 0, 0);
      }
    }
    __syncthreads();
  }
#pragma unroll
  for (int nj = 0; nj < 4; ++nj)
#pragma unroll
    for (int r = 0; r < 4; ++r) {
      int row = wr + ((l >> 4) << 2) + r;
      int col = wc + nj * 16 + (l & 15);
      tld[row][col] = acc[nj][r] + bo[col];
    }
  __syncthreads();

  // ---- gate1 + LN2 (8 threads/row; n1 and x-row live in registers) ----
  int row = t >> 3, part = t & 7;
  int srcn = cl[m0 + row];
  float xv[16], n1r[16];
  {
    const float* xr = x + (size_t)srcn * CC + part * 16;
#pragma unroll
    for (int j = 0; j < 16; ++j) xv[j] = xr[j];
    float dot = 0.f;
#pragma unroll
    for (int j = 0; j < 16; ++j) {
      int c = part * 16 + j;
      dot += tld[row][c] * w0g1[c] + xv[j] * w1g1[c];
    }
    dot += __shfl_xor(dot, 1); dot += __shfl_xor(dot, 2); dot += __shfl_xor(dot, 4);
    float g = 1.0f / (1.0f + __expf(-dot));
    float s = 0.f, q = 0.f;
#pragma unroll
    for (int j = 0; j < 16; ++j) {
      int c = part * 16 + j;
      float nv = tld[row][c] * g + xv[j] * (1.0f - g);
      n1r[j] = nv;
      s += nv; q += nv * nv;
    }
    s += __shfl_xor(s, 1); s += __shfl_xor(s, 2); s += __shfl_xor(s, 4);
    q += __shfl_xor(q, 1); q += __shfl_xor(q, 2); q += __shfl_xor(q, 4);
    float mu = s * (1.0f / CC);
    float var = q * (1.0f / CC) - mu * mu;
    float rs = rsqrtf(var + 1e-5f);
#pragma unroll
    for (int j = 0; j < 16; ++j) {
      int c = part * 16 + j;
      float yv = (n1r[j] - mu) * rs * lnGs[c] + lnBs[c];
      int ch = c >> 3;
      y2L[row * 128 + (((ch & ~7) | ((ch ^ row) & 7)) << 3) + (c & 7)] = f2bf(yv);
    }
  }
  __syncthreads();

  // ---- W1 GEMM + GELU: y2L[32][128] @ W1T[512][128]^T -> ffh (overlay As) ----
  for (int nc = 0; nc < 4; ++nc) {
    f32x4 a1[4];
#pragma unroll
    for (int nj = 0; nj < 4; ++nj) a1[nj] = (f32x4){0.f, 0.f, 0.f, 0.f};
    for (int k0 = 0; k0 < 128; k0 += 32) {
#pragma unroll
      for (int i = 0; i < 2; ++i) {
        int c = t + i * 256;
        int r = c >> 2, kc = c & 3;
        *(uint4*)&Bb[r * 32 + kc * 8] = *(const uint4*)&W1T[(size_t)(nc * 128 + r) * 128 + k0 + kc * 8];
      }
      __syncthreads();
      {
        int arow = wr + (l & 15);
        int gch = (k0 >> 3) + (l >> 4);
        short8 aF = *(const short8*)&y2L[arow * 128 + (((gch & ~7) | ((gch ^ arow) & 7)) << 3)];
#pragma unroll
        for (int nj = 0; nj < 4; ++nj) {
          short8 bF = *(const short8*)&Bb[(wc + nj * 16 + (l & 15)) * 32 + (l >> 4) * 8];
          a1[nj] = __builtin_amdgcn_mfma_f32_16x16x32_bf16(aF, bF, a1[nj], 0, 0, 0);
        }
      }
      __syncthreads();
    }
#pragma unroll
    for (int nj = 0; nj < 4; ++nj)
#pragma unroll
      for (int r = 0; r < 4; ++r) {
        int rw = wr + ((l >> 4) << 2) + r;
        int n = nc * 128 + wc + nj * 16 + (l & 15);
        float v = a1[nj][r] + b1[n];
        v = 0.5f * v * (1.0f + erff(v * 0.70710678118654752f));
        int ch = n >> 3;
        As[rw * 512 + (((ch & ~7) | ((ch ^ rw) & 7)) << 3) + (n & 7)] = f2bf(v);
      }
  }
  __syncthreads();

  // ---- W2 GEMM: ffh[32][512] @ W2T[128][512]^T -> tld[32][128] ----
  f32x4 a2[4];
#pragma unroll
  for (int nj = 0; nj < 4; ++nj) a2[nj] = (f32x4){0.f, 0.f, 0.f, 0.f};
  for (int k0 = 0; k0 < 512; k0 += 32) {
#pragma unroll
    for (int i = 0; i < 2; ++i) {
      int c = t + i * 256;
      int r = c >> 2, kc = c & 3;
      *(uint4*)&Bb[r * 32 + kc * 8] = *(const uint4*)&W2T[(size_t)r * 512 + k0 + kc * 8];
    }
    __syncthreads();
    {
      int arow = wr + (l & 15);
      int gch = (k0 >> 3) + (l >> 4);
      short8 aF = *(const short8*)&As[arow * 512 + (((gch & ~7) | ((gch ^ arow) & 7)) << 3)];
#pragma unroll
      for (int nj = 0; nj < 4; ++nj) {
        short8 bF = *(const short8*)&Bb[(wc + nj * 16 + (l & 15)) * 32 + (l >> 4) * 8];
        a2[nj] = __builtin_amdgcn_mfma_f32_16x16x32_bf16(aF, bF, a2[nj], 0, 0, 0);
      }
    }
    __syncthreads();
  }
#pragma unroll
  for (int nj = 0; nj < 4; ++nj)
#pragma unroll
    for (int r = 0; r < 4; ++r) {
      int rw = wr + ((l >> 4) << 2) + r;
      int col = wc + nj * 16 + (l & 15);
      tld[rw][col] = a2[nj][r] + b2[col];
    }
  __syncthreads();

  // ---- gate2 + final add ----
  {
    float dot = 0.f;
#pragma unroll
    for (int j = 0; j < 16; ++j) {
      int c = part * 16 + j;
      dot += tld[row][c] * w0g2[c] + n1r[j] * w1g2[c];
    }
    dot += __shfl_xor(dot, 1); dot += __shfl_xor(dot, 2); dot += __shfl_xor(dot, 4);
    float g = 1.0f / (1.0f + __expf(-dot));
#pragma unroll
    for (int j = 0; j < 16; ++j) {
      int c = part * 16 + j;
      out[(size_t)srcn * CC + c] = xv[j] + tld[row][c] * g + n1r[j] * (1.0f - g);
    }
  }
}

extern "C" void kernel_launch(void* const* d_in, const int* in_sizes, int n_in,
                              void* d_out, int out_size, void* d_ws, size_t ws_size,
                              hipStream_t stream) {
  const float* x       = (const float*)d_in[0];
  const int*   edge    = (const int*)d_in[1];
  const int*   clusters= (const int*)d_in[2];
  const float* adj_emb = (const float*)d_in[3];
  const float* ln1_g   = (const float*)d_in[4];
  const float* ln1_b   = (const float*)d_in[5];
  const float* Wq      = (const float*)d_in[6];
  const float* bq      = (const float*)d_in[7];
  const float* Wkv     = (const float*)d_in[8];
  const float* bkv     = (const float*)d_in[9];
  const float* We      = (const float*)d_in[10];
  const float* be      = (const float*)d_in[11];
  const float* Wo      = (const float*)d_in[12];
  const float* bo      = (const float*)d_in[13];
  const float* gate1   = (const float*)d_in[14];
  const float* ln2_g   = (const float*)d_in[15];
  const float* ln2_b   = (const float*)d_in[16];
  const float* W1      = (const float*)d_in[17];
  const float* b1      = (const float*)d_in[18];
  const float* W2      = (const float*)d_in[19];
  const float* b2      = (const float*)d_in[20];
  const float* gate2   = (const float*)d_in[21];

  char* wsb = (char*)d_ws;
  unsigned* adjw  = (unsigned*)wsb;                 // 64 KB
  float* e01   = (float*)(wsb + 65536);             // 4 KB
  float* cosF  = (float*)(wsb + 69632);             // 32 KB
  float* sinF  = (float*)(wsb + 102400);            // 32 KB
  ushort* WqkvT= (ushort*)(wsb + 135168);           // 384 KB
  ushort* WoT  = (ushort*)(wsb + 528384);           // 128 KB
  ushort* W1T  = (ushort*)(wsb + 659456);           // 128 KB
  ushort* W2T  = (ushort*)(wsb + 790528);           // 128 KB
  ushort* y    = (ushort*)(wsb + 921600);           // 1 MB
  ushort* P    = (ushort*)(wsb + 1970176);          // 12 MB (4096x1536 bf16)
  ushort* AO   = (ushort*)(wsb + 14553088);         // 4 MB

  pre_kernel<<<1424, 256, 0, stream>>>(Wq, Wkv, Wo, W1, W2, adj_emb, We, be,
                                       x, clusters, ln1_g, ln1_b,
                                       WqkvT, WoT, W1T, W2T, e01, cosF, sinF, adjw, y);
  qkv_adj_kernel<<<640, 256, 0, stream>>>(y, WqkvT, bq, bkv, cosF, sinF, edge, adjw, P);
  attn_kernel<<<KCL * HH, 512, 0, stream>>>(P, adjw, e01, AO);
  tail_kernel<<<128, 256, 0, stream>>>(AO, WoT, bo, W1T, b1, W2T, b2,
                                       x, clusters, gate1, gate2, ln2_g, ln2_b, (float*)d_out);
}